// Round 4
// baseline (1305.141 us; speedup 1.0000x reference)
//
#include <hip/hip_runtime.h>
#include <hip/hip_bf16.h>
#include <math.h>

// Problem constants
#define BB   2
#define TT   256
#define DD   256
#define HH   4
#define NN   32768
#define nn   8192
#define VV   32000
#define L_LAYERS 6
#define LN_EPS 1e-5f

typedef __attribute__((ext_vector_type(8))) short bf16x8;
typedef __attribute__((ext_vector_type(4))) float f32x4;

__device__ __forceinline__ unsigned short f2bf(float f) {
    union { float f; unsigned int u; } v; v.f = f;
    unsigned int r = (v.u + 0x7FFFu + ((v.u >> 16) & 1u)) >> 16;
    return (unsigned short)r;
}
__device__ __forceinline__ float bf2f(unsigned short h) {
    union { unsigned int u; float f; } v; v.u = ((unsigned int)h) << 16;
    return v.f;
}
// 16B-aligned load -> bf16x8 (ds_read_b128 from LDS)
__device__ __forceinline__ bf16x8 ld_frag16(const unsigned short* p) {
    union { bf16x8 v; uint4 u; } r;
    r.u = *(const uint4*)p;
    return r.v;
}
// async global->LDS, 16 bytes per lane; LDS base wave-uniform, HW adds lane*16B.
__device__ __forceinline__ void gll16(const unsigned short* g, unsigned short* l) {
    __builtin_amdgcn_global_load_lds(
        (const __attribute__((address_space(1))) unsigned int*)g,
        (__attribute__((address_space(3))) unsigned int*)l, 16, 0, 0);
}

// ---------------- block reduction helpers (256 threads = 4 waves) ----------------
__device__ __forceinline__ float block_sum(float v) {
    __shared__ float sh[4];
    #pragma unroll
    for (int o = 32; o > 0; o >>= 1) v += __shfl_down(v, o, 64);
    __syncthreads();
    if ((threadIdx.x & 63) == 0) sh[threadIdx.x >> 6] = v;
    __syncthreads();
    return sh[0] + sh[1] + sh[2] + sh[3];
}
__device__ __forceinline__ float block_max(float v) {
    __shared__ float sh[4];
    #pragma unroll
    for (int o = 32; o > 0; o >>= 1) v = fmaxf(v, __shfl_down(v, o, 64));
    __syncthreads();
    if ((threadIdx.x & 63) == 0) sh[threadIdx.x >> 6] = v;
    __syncthreads();
    return fmaxf(fmaxf(sh[0], sh[1]), fmaxf(sh[2], sh[3]));
}
__device__ __forceinline__ float ln_val(float x) {
    float m = block_sum(x) * (1.0f / 256.0f);
    float d = x - m;
    float var = block_sum(d * d) * (1.0f / 256.0f);
    return d * rsqrtf(var + LN_EPS);
}

// ---------------- small row kernels ----------------
__global__ __launch_bounds__(256) void embed_ln_k(const int* __restrict__ idx,
                                                  const float* __restrict__ wte,
                                                  float* __restrict__ v,
                                                  unsigned short* __restrict__ vb) {
    int row = blockIdx.x;
    int tok = idx[row];
    float x = wte[(size_t)tok * DD + threadIdx.x];
    float o = ln_val(x);
    size_t i = (size_t)row * DD + threadIdx.x;
    v[i] = o;
    vb[i] = f2bf(o);
}

__global__ __launch_bounds__(256) void ln_rows_k(const float* __restrict__ in,
                                                 unsigned short* __restrict__ ob) {
    size_t i = (size_t)blockIdx.x * DD + threadIdx.x;
    ob[i] = f2bf(ln_val(in[i]));
}

__global__ __launch_bounds__(256) void add_ln_ln_k(float* __restrict__ v,
                                                   const float* __restrict__ yenc,
                                                   unsigned short* __restrict__ vb) {
    size_t i = (size_t)blockIdx.x * DD + threadIdx.x;
    float t1 = ln_val(yenc[i]);
    float w = v[i] + t1;
    float o = ln_val(w);
    v[i] = o;
    vb[i] = f2bf(o);
}

// ---------------- transpose+convert: dst[c][r] bf16 = src[r][c] fp32 ----------------
__global__ __launch_bounds__(256) void tconv_k(const float* __restrict__ src,
                                               unsigned short* __restrict__ dst,
                                               int R, int C, long sstride, long dstride) {
    src += (size_t)blockIdx.z * sstride;
    dst += (size_t)blockIdx.z * dstride;
    __shared__ unsigned short tile[64][66];
    int c0 = blockIdx.x * 64, r0 = blockIdx.y * 64;
    int c = threadIdx.x & 63, q = threadIdx.x >> 6;
    #pragma unroll
    for (int i = 0; i < 16; i++) {
        int r = q + i * 4;
        tile[r][c] = f2bf(src[(size_t)(r0 + r) * C + c0 + c]);
    }
    __syncthreads();
    #pragma unroll
    for (int i = 0; i < 16; i++) {
        int r = q + i * 4;
        dst[(size_t)(c0 + r) * R + r0 + c] = tile[c][r];
    }
}

// ======================================================================
// 2-phase double-buffered BT-GEMM mainloop (T3-minimum recipe):
//   prologue: STAGE(buf0) via global_load_lds; __syncthreads (vmcnt drain)
//   iter k:   STAGE(buf[nxt]) -> ds_read buf[cur] -> MFMA -> __syncthreads
// One barrier per k-step; next-tile loads in flight across the whole MFMA phase.
// Linear LDS [128][32] per buffer (R1-verified: 0 bank conflicts, correct map).
// As/Bs each hold 2 buffers of 4096 shorts (8 KB); total LDS 32 KB.
// ======================================================================
__device__ __forceinline__ void bt_mainloop(const unsigned short* Ap, long lda,
                                            const unsigned short* Bp, long ldb,
                                            int ksteps,
                                            unsigned short* As,
                                            unsigned short* Bs,
                                            f32x4 (&acc)[4][4]) {
    int tid = threadIdx.x, w = tid >> 6, l = tid & 63;
    int rowoff = (w >> 1) * 64, coloff = (w & 1) * 64;
    int fr = l & 15, fq = (l >> 4) * 8;
    // staging: wave w covers rows [w*16, w*16+16) and +64; lane l -> row +(l>>2), col (l&3)*8
    int srow = w * 16 + (l >> 2), scol = (l & 3) * 8;
    const unsigned short* ga = Ap + (size_t)srow * lda + scol;
    const unsigned short* gb = Bp + (size_t)srow * ldb + scol;
    unsigned short* la = As + w * 512;
    unsigned short* lb = Bs + w * 512;
    long a64 = 64 * lda, b64 = 64 * ldb;
    // prologue: stage buffer 0
    gll16(ga, la);        gll16(ga + a64, la + 2048);
    gll16(gb, lb);        gll16(gb + b64, lb + 2048);
    ga += 32; gb += 32;
    __syncthreads();                        // drains vmcnt -> buf0 complete
    for (int k = 0; k < ksteps; k++) {
        int cur = (k & 1) * 4096;
        int nxt = 4096 - cur;
        if (k + 1 < ksteps) {               // issue next-tile staging FIRST
            gll16(ga, la + nxt);        gll16(ga + a64, la + nxt + 2048);
            gll16(gb, lb + nxt);        gll16(gb + b64, lb + nxt + 2048);
            ga += 32; gb += 32;
        }
        bf16x8 af[4], bfv[4];
        #pragma unroll
        for (int mi = 0; mi < 4; mi++)
            af[mi] = ld_frag16(&As[cur + (rowoff + mi * 16 + fr) * 32 + fq]);
        #pragma unroll
        for (int nj = 0; nj < 4; nj++)
            bfv[nj] = ld_frag16(&Bs[cur + (coloff + nj * 16 + fr) * 32 + fq]);
        #pragma unroll
        for (int mi = 0; mi < 4; mi++)
            #pragma unroll
            for (int nj = 0; nj < 4; nj++)
                acc[mi][nj] = __builtin_amdgcn_mfma_f32_16x16x32_bf16(af[mi], bfv[nj], acc[mi][nj], 0, 0, 0);
        __syncthreads();                    // vmcnt(0): next buf staged; lgkm: reads done
    }
}

// ---------------- head GEMM with LDS-staged coalesced epilogue ----------------
// mode 0: xb = bf16(relu(vb @ WxT[h])), AND xrb = rope(xb) fused.
// mode 1: ybf = bf16(relu(lAb @ WyT[h]) * xb), coalesced mulx reads + stores.
__global__ __launch_bounds__(256) void gemm_head_bt(const unsigned short* __restrict__ A,
                                                    const unsigned short* __restrict__ Wt,
                                                    unsigned short* __restrict__ Cx,
                                                    const unsigned short* __restrict__ mulx,
                                                    unsigned short* __restrict__ Cy,
                                                    int mode) {
    int h = blockIdx.z;
    int n0 = blockIdx.x * 128, m0 = blockIdx.y * 128;
    // 32 KB shared: 2x dbuf A (16 KB) + 2x dbuf B (16 KB); then reused as Cs[128][128].
    __shared__ __attribute__((aligned(16))) unsigned short smem[16384];
    unsigned short* As = smem;
    unsigned short* Bs = smem + 8192;
    f32x4 acc[4][4] = {};
    bt_mainloop(A + (size_t)m0 * DD, DD,
                Wt + (size_t)h * nn * DD + (size_t)n0 * DD, DD, 8, As, Bs, acc);
    __syncthreads();   // mainloop done; smem free for output staging

    int tid = threadIdx.x, lane = tid & 63, w = tid >> 6;
    int rowoff = (w >> 1) * 64, coloff = (w & 1) * 64;
    int r4 = (lane >> 4) * 4, cc = lane & 15;
    unsigned short (*Cs)[128] = (unsigned short (*)[128])smem;
    #pragma unroll
    for (int mi = 0; mi < 4; mi++)
        #pragma unroll
        for (int nj = 0; nj < 4; nj++)
            #pragma unroll
            for (int rr = 0; rr < 4; rr++)
                Cs[rowoff + mi * 16 + r4 + rr][coloff + nj * 16 + cc] =
                    f2bf(fmaxf(acc[mi][nj][rr], 0.0f));
    __syncthreads();

    // writer arrangement: thread covers chunks {tid + j*256}, j=0..7.
    int colc = (tid & 15) * 8;
    #pragma unroll
    for (int j = 0; j < 8; j++) {
        int row = (tid >> 4) + j * 16;
        int m = m0 + row;
        int b = m >> 8, t = m & 255;
        union { uint4 u; unsigned short s[8]; } ch;
        ch.u = *(const uint4*)&Cs[row][colc];
        if (mode == 0) {
            size_t bhtn = (((size_t)(b * HH + h)) * TT + t) * (size_t)nn + n0 + colc;
            *(uint4*)(Cx + bhtn) = ch.u;                 // xb
            // fused RoPE -> xrb
            union { uint4 u; unsigned short s[8]; } ro;
            float tf = (float)t;
            int pbase = ((n0 + colc) >> 1);
            #pragma unroll
            for (int k2 = 0; k2 < 4; k2++) {
                int p = pbase + k2;
                float inv = __expf(-(float)p * (9.210340371976184f / 4096.0f));
                float ang = tf * inv;
                float s = __sinf(ang), c = __cosf(ang);
                float xe = bf2f(ch.s[2 * k2]), xo = bf2f(ch.s[2 * k2 + 1]);
                ro.s[2 * k2]     = f2bf(xe * c - xo * s);
                ro.s[2 * k2 + 1] = f2bf(xo * c + xe * s);
            }
            *(uint4*)(Cy + bhtn) = ro.u;                 // xrb
        } else {
            size_t bhtn = (((size_t)(b * HH + h)) * TT + t) * (size_t)nn + n0 + colc;
            union { uint4 u; unsigned short s[8]; } mx, oy;
            mx.u = *(const uint4*)(mulx + bhtn);
            #pragma unroll
            for (int k2 = 0; k2 < 8; k2++)
                oy.s[k2] = f2bf(bf2f(ch.s[k2]) * bf2f(mx.s[k2]));
            *(uint4*)(Cy + ((size_t)(b * TT + t)) * NN + (size_t)h * nn + n0 + colc) = oy.u;
        }
    }
}

// ---------------- scores: sc += scale * xrb @ xrb^T (split-K 32, causal tiles) --------
__global__ __launch_bounds__(256) void scores_bt(const unsigned short* __restrict__ xrb,
                                                 float* __restrict__ sc) {
    int zh = blockIdx.z, kc = blockIdx.y, tile = blockIdx.x;
    int t0 = (tile >= 1) ? 128 : 0;
    int s0 = (tile == 2) ? 128 : 0;
    const unsigned short* Xz = xrb + (size_t)zh * TT * nn + (size_t)kc * 256;
    __shared__ __attribute__((aligned(16))) unsigned short As[8192], Bs[8192];
    f32x4 acc[4][4] = {};
    bt_mainloop(Xz + (size_t)t0 * nn, nn, Xz + (size_t)s0 * nn, nn, 8, As, Bs, acc);
    const float scale = 0.011048543456039805f;   // 1/sqrt(8192)
    int tid = threadIdx.x, lane = tid & 63, w = tid >> 6;
    int rowoff = (w >> 1) * 64, coloff = (w & 1) * 64;
    int r4 = (lane >> 4) * 4, cc = lane & 15;
    float* scz = sc + (size_t)zh * TT * TT;
    #pragma unroll
    for (int mi = 0; mi < 4; mi++)
        #pragma unroll
        for (int nj = 0; nj < 4; nj++)
            #pragma unroll
            for (int rr = 0; rr < 4; rr++) {
                int t = t0 + rowoff + mi * 16 + r4 + rr;
                int s = s0 + coloff + nj * 16 + cc;
                atomicAdd(&scz[(size_t)t * TT + s], acc[mi][nj][rr] * scale);
            }
}

// ---------------- encoder GEMM: yenc += ybf(512x32768) @ encT^T (split-K 64) ----------
__global__ __launch_bounds__(256) void gemm_enc_bt(const unsigned short* __restrict__ A,
                                                   const unsigned short* __restrict__ Bt,
                                                   float* __restrict__ C) {
    int n0 = blockIdx.x * 128, m0 = blockIdx.y * 128;
    long kbase = (long)blockIdx.z * 512;
    __shared__ __attribute__((aligned(16))) unsigned short As[8192], Bs[8192];
    f32x4 acc[4][4] = {};
    bt_mainloop(A + (size_t)m0 * NN + kbase, NN,
                Bt + (size_t)n0 * NN + kbase, NN, 16, As, Bs, acc);
    int tid = threadIdx.x, lane = tid & 63, w = tid >> 6;
    int rowoff = (w >> 1) * 64, coloff = (w & 1) * 64;
    int r4 = (lane >> 4) * 4, cc = lane & 15;
    #pragma unroll
    for (int mi = 0; mi < 4; mi++)
        #pragma unroll
        for (int nj = 0; nj < 4; nj++)
            #pragma unroll
            for (int rr = 0; rr < 4; rr++) {
                int row = m0 + rowoff + mi * 16 + r4 + rr;
                int col = n0 + coloff + nj * 16 + cc;
                atomicAdd(&C[(size_t)row * DD + col], acc[mi][nj][rr]);
            }
}

// ---------------- readout: out = vb @ WroT^T, fp32 out ----------------
__global__ __launch_bounds__(256) void gemm_ro_bt(const unsigned short* __restrict__ A,
                                                  const unsigned short* __restrict__ Wt,
                                                  float* __restrict__ out) {
    int n0 = blockIdx.x * 128, m0 = blockIdx.y * 128;
    __shared__ __attribute__((aligned(16))) unsigned short As[8192], Bs[8192];
    f32x4 acc[4][4] = {};
    bt_mainloop(A + (size_t)m0 * DD, DD, Wt + (size_t)n0 * DD, DD, 8, As, Bs, acc);
    int tid = threadIdx.x, lane = tid & 63, w = tid >> 6;
    int rowoff = (w >> 1) * 64, coloff = (w & 1) * 64;
    int r4 = (lane >> 4) * 4, cc = lane & 15;
    #pragma unroll
    for (int mi = 0; mi < 4; mi++)
        #pragma unroll
        for (int nj = 0; nj < 4; nj++)
            #pragma unroll
            for (int rr = 0; rr < 4; rr++) {
                int m = m0 + rowoff + mi * 16 + r4 + rr;
                int col = n0 + coloff + nj * 16 + cc;
                out[(size_t)m * VV + col] = acc[mi][nj][rr];
            }
}

// ---------------- causal softmax per (b,h,t) + mean over h -> am (B,T,T) ----------------
__global__ __launch_bounds__(256) void softmax_mean_k(const float* __restrict__ sc,
                                                      float* __restrict__ am) {
    int bt = blockIdx.x;
    int b = bt >> 8, t = bt & 255;
    int s = threadIdx.x;
    float acc = 0.0f;
    for (int h = 0; h < HH; h++) {
        const float* row = sc + (((size_t)(b * HH + h)) * TT + t) * TT;
        float val = (s <= t) ? row[s] : -1e30f;
        float mx = block_max(val);
        float e = (s <= t) ? expf(val - mx) : 0.0f;
        float sum = block_sum(e);
        acc += e / sum;
    }
    am[((size_t)b * TT + t) * TT + s] = acc * 0.25f;
}

// ---------------- fp32 NN GEMM — used only for a = am @ v ----------------
__global__ __launch_bounds__(256) void gemm_nn_k(const float* __restrict__ A,
                                                 const float* __restrict__ B,
                                                 float* __restrict__ C,
                                                 int M, int N, int K,
                                                 long lda, long ldb, long ldc,
                                                 long sAz, long sBz, long sCz) {
    int batch = blockIdx.z;
    A += (size_t)batch * sAz;
    B += (size_t)batch * sBz;
    C += (size_t)batch * sCz;
    int m0 = blockIdx.y * 64, n0 = blockIdx.x * 64;
    __shared__ float As[16][68];
    __shared__ float Bs[16][64];
    int tid = threadIdx.x;
    int tx = tid & 15, ty = tid >> 4;
    int ar = tid >> 2, ac = (tid & 3) * 4;
    int br = tid >> 4, bc = (tid & 15) * 4;
    float acc[4][4] = {};
    for (int k0 = 0; k0 < K; k0 += 16) {
        float4 av = *(const float4*)(A + (size_t)(m0 + ar) * lda + k0 + ac);
        float4 bv = *(const float4*)(B + (size_t)(k0 + br) * ldb + n0 + bc);
        As[ac + 0][ar] = av.x; As[ac + 1][ar] = av.y;
        As[ac + 2][ar] = av.z; As[ac + 3][ar] = av.w;
        *(float4*)&Bs[br][bc] = bv;
        __syncthreads();
        #pragma unroll
        for (int k = 0; k < 16; k++) {
            float4 a4 = *(const float4*)&As[k][ty * 4];
            float4 b4 = *(const float4*)&Bs[k][tx * 4];
            float aa[4] = {a4.x, a4.y, a4.z, a4.w};
            float bb[4] = {b4.x, b4.y, b4.z, b4.w};
            #pragma unroll
            for (int i = 0; i < 4; i++)
                #pragma unroll
                for (int j = 0; j < 4; j++)
                    acc[i][j] = fmaf(aa[i], bb[j], acc[i][j]);
        }
        __syncthreads();
    }
    #pragma unroll
    for (int i = 0; i < 4; i++) {
        int m = m0 + ty * 4 + i;
        #pragma unroll
        for (int j = 0; j < 4; j++) {
            int col = n0 + tx * 4 + j;
            C[(size_t)m * ldc + col] = acc[i][j];
        }
    }
}

// ---------------- launch ----------------
extern "C" void kernel_launch(void* const* d_in, const int* in_sizes, int n_in,
                              void* d_out, int out_size, void* d_ws, size_t ws_size,
                              hipStream_t stream) {
    const int*   idx  = (const int*)d_in[0];
    const float* wte  = (const float*)d_in[1];
    const float* enc  = (const float*)d_in[2];
    const float* Wx   = (const float*)d_in[3];
    const float* Wy   = (const float*)d_in[4];
    const float* Wro  = (const float*)d_in[5];
    float* out = (float*)d_out;

    // float region (1,048,576 floats = 4 MB); sc and yenc adjacent -> one memset
    float* ws   = (float*)d_ws;
    float* v    = ws;                  // 131072
    float* sc   = v    + 131072;       // 524288
    float* yenc = sc   + 524288;       // 131072
    float* am   = yenc + 131072;       // 131072
    float* a    = am   + 131072;       // 131072
    // short region
    unsigned short* sbase = (unsigned short*)(a + 131072);
    unsigned short* vb   = sbase;                 // 131072
    unsigned short* lAb  = vb   + 131072;         // 131072
    unsigned short* xb   = lAb  + 131072;         // 16777216 (B,H,T,n); WroT aliases at end
    unsigned short* xrb  = xb   + 16777216;       // 16777216 (B,H,T,n); ybf aliases
    unsigned short* WxT  = xrb  + 16777216;       // 8388608  [h][8192][256]
    unsigned short* WyT  = WxT  + 8388608;        // 8388608
    unsigned short* encT = WyT  + 8388608;        // 8388608  [256][32768]
    unsigned short* ybf  = xrb;                   // alias: xrb dead after scores
    unsigned short* WroT = xb;                    // alias: xb dead after last y-GEMM

    // pre-pass: weight transpose+convert (once per launch, amortized over 6 layers)
    tconv_k<<<dim3(nn / 64, DD / 64, HH), 256, 0, stream>>>(Wx, WxT, DD, nn,
        (long)DD * nn, (long)nn * DD);
    tconv_k<<<dim3(DD / 64, NN / 64, 1), 256, 0, stream>>>(enc, encT, NN, DD, 0L, 0L);
    tconv_k<<<dim3(nn / 64, DD / 64, HH), 256, 0, stream>>>(Wy, WyT, DD, nn,
        (long)DD * nn, (long)nn * DD);

    // v = ln(wte[idx]) (+ bf16)
    embed_ln_k<<<BB * TT, 256, 0, stream>>>(idx, wte, v, vb);

    for (int l = 0; l < L_LAYERS; l++) {
        // xb = bf16(relu(vb @ WxT[h])), xrb = rope(xb) — fused
        gemm_head_bt<<<dim3(nn / 128, (BB * TT) / 128, HH), 256, 0, stream>>>(
            vb, WxT, xb, nullptr, xrb, 0);

        // zero sc + yenc in one fill (adjacent)
        hipMemsetAsync(sc, 0, (size_t)(524288 + 131072) * sizeof(float), stream);

        // sc = scale * xrb @ xrb^T (split-K 32, causal tiles)
        scores_bt<<<dim3(3, 32, BB * HH), 256, 0, stream>>>(xrb, sc);

        // softmax (causal) + mean over heads
        softmax_mean_k<<<BB * TT, 256, 0, stream>>>(sc, am);

        // a = am @ v (per b), fp32
        gemm_nn_k<<<dim3(DD / 64, TT / 64, BB), 256, 0, stream>>>(
            am, v, a, TT, DD, TT,
            (long)TT, (long)DD, (long)DD,
            (long)TT * TT, (long)TT * DD, (long)TT * DD);

        // lAb = bf16(ln(a))
        ln_rows_k<<<BB * TT, 256, 0, stream>>>(a, lAb);

        // ybf = bf16(relu(lAb @ WyT[h]) * xb)   (ybf aliases xrb)
        gemm_head_bt<<<dim3(nn / 128, (BB * TT) / 128, HH), 256, 0, stream>>>(
            lAb, WyT, nullptr, xb, ybf, 1);

        // yenc = ybf @ enc (split-K 64)
        gemm_enc_bt<<<dim3(2, 4, 64), 256, 0, stream>>>(ybf, encT, yenc);

        // v = ln(v + ln(yenc)) (+ bf16)
        add_ln_ln_k<<<BB * TT, 256, 0, stream>>>(v, yenc, vb);
    }

    // WroT = transpose+bf16(Wro) into xb region (xb dead now)
    tconv_k<<<dim3(VV / 64, DD / 64, 1), 256, 0, stream>>>(Wro, WroT, DD, VV, 0L, 0L);

    // out = vb @ WroT^T (fp32 out)
    gemm_ro_bt<<<dim3(VV / 128, (BB * TT) / 128, 1), 256, 0, stream>>>(vb, WroT, out);
}

// Round 5
// 1171.762 us; speedup vs baseline: 1.1138x; 1.1138x over previous
//
#include <hip/hip_runtime.h>
#include <hip/hip_bf16.h>
#include <math.h>

// Problem constants
#define BB   2
#define TT   256
#define DD   256
#define HH   4
#define NN   32768
#define nn   8192
#define VV   32000
#define L_LAYERS 6
#define LN_EPS 1e-5f

#define SKC  4      // scores split-K partials
#define EKC  16     // encoder split-K partials

typedef __attribute__((ext_vector_type(8))) short bf16x8;
typedef __attribute__((ext_vector_type(4))) float f32x4;

__device__ __forceinline__ unsigned short f2bf(float f) {
    union { float f; unsigned int u; } v; v.f = f;
    unsigned int r = (v.u + 0x7FFFu + ((v.u >> 16) & 1u)) >> 16;
    return (unsigned short)r;
}
__device__ __forceinline__ float bf2f(unsigned short h) {
    union { unsigned int u; float f; } v; v.u = ((unsigned int)h) << 16;
    return v.f;
}
__device__ __forceinline__ bf16x8 ld_frag(const unsigned short* p) {
    union { bf16x8 v; uint2 u[2]; } r;
    r.u[0] = *(const uint2*)(p);
    r.u[1] = *(const uint2*)(p + 4);
    return r.v;
}

// ---------------- block reduction helpers (256 threads = 4 waves) ----------------
__device__ __forceinline__ float block_sum(float v) {
    __shared__ float sh[4];
    #pragma unroll
    for (int o = 32; o > 0; o >>= 1) v += __shfl_down(v, o, 64);
    __syncthreads();
    if ((threadIdx.x & 63) == 0) sh[threadIdx.x >> 6] = v;
    __syncthreads();
    return sh[0] + sh[1] + sh[2] + sh[3];
}
__device__ __forceinline__ float block_max(float v) {
    __shared__ float sh[4];
    #pragma unroll
    for (int o = 32; o > 0; o >>= 1) v = fmaxf(v, __shfl_down(v, o, 64));
    __syncthreads();
    if ((threadIdx.x & 63) == 0) sh[threadIdx.x >> 6] = v;
    __syncthreads();
    return fmaxf(fmaxf(sh[0], sh[1]), fmaxf(sh[2], sh[3]));
}
__device__ __forceinline__ float ln_val(float x) {
    float m = block_sum(x) * (1.0f / 256.0f);
    float d = x - m;
    float var = block_sum(d * d) * (1.0f / 256.0f);
    return d * rsqrtf(var + LN_EPS);
}

// ---------------- small row kernels ----------------
__global__ __launch_bounds__(256) void embed_ln_k(const int* __restrict__ idx,
                                                  const float* __restrict__ wte,
                                                  float* __restrict__ v,
                                                  unsigned short* __restrict__ vb) {
    int row = blockIdx.x;
    int tok = idx[row];
    float x = wte[(size_t)tok * DD + threadIdx.x];
    float o = ln_val(x);
    size_t i = (size_t)row * DD + threadIdx.x;
    v[i] = o;
    vb[i] = f2bf(o);
}

__global__ __launch_bounds__(256) void ln_rows_k(const float* __restrict__ in,
                                                 unsigned short* __restrict__ ob) {
    size_t i = (size_t)blockIdx.x * DD + threadIdx.x;
    ob[i] = f2bf(ln_val(in[i]));
}

// v = ln(v + ln(sum_kc yencp)) (+ bf16)  — folds encoder split-K reduction
__global__ __launch_bounds__(256) void add_ln_ln_k(float* __restrict__ v,
                                                   const float* __restrict__ yencp,
                                                   unsigned short* __restrict__ vb) {
    size_t i = (size_t)blockIdx.x * DD + threadIdx.x;
    float ysum = 0.0f;
    #pragma unroll
    for (int kc = 0; kc < EKC; kc++)
        ysum += yencp[(size_t)kc * (BB * TT * DD) + i];
    float t1 = ln_val(ysum);
    float w = v[i] + t1;
    float o = ln_val(w);
    v[i] = o;
    vb[i] = f2bf(o);
}

// ---------------- transpose+convert: dst[c][r] bf16 = src[r][c] fp32 ----------------
__global__ __launch_bounds__(256) void tconv_k(const float* __restrict__ src,
                                               unsigned short* __restrict__ dst,
                                               int R, int C, long sstride, long dstride) {
    src += (size_t)blockIdx.z * sstride;
    dst += (size_t)blockIdx.z * dstride;
    __shared__ unsigned short tile[64][66];
    int c0 = blockIdx.x * 64, r0 = blockIdx.y * 64;
    int c = threadIdx.x & 63, q = threadIdx.x >> 6;
    #pragma unroll
    for (int i = 0; i < 16; i++) {
        int r = q + i * 4;
        tile[r][c] = f2bf(src[(size_t)(r0 + r) * C + c0 + c]);
    }
    __syncthreads();
    #pragma unroll
    for (int i = 0; i < 16; i++) {
        int r = q + i * 4;
        dst[(size_t)(c0 + r) * R + r0 + c] = tile[c][r];
    }
}

// ======================================================================
// LDS-staged BT-GEMM main loop (reg-staged, pipelined) — R3-verified best.
// Block tile 128x128, 4 waves, each wave 64x64 via 4x4 16x16x32 MFMA frags.
// ======================================================================
__device__ __forceinline__ void bt_mainloop(const unsigned short* Ap, long lda,
                                            const unsigned short* Bp, long ldb,
                                            int ksteps,
                                            unsigned short (*As)[36],
                                            unsigned short (*Bs)[36],
                                            f32x4 (&acc)[4][4]) {
    int tid = threadIdx.x;
    int ra = tid >> 1, pa = (tid & 1) * 16;
    int lane = tid & 63, w = tid >> 6;
    int rowoff = (w >> 1) * 64, coloff = (w & 1) * 64;
    int fr = lane & 15, fq = (lane >> 4) * 8;
    const unsigned short* ga = Ap + (size_t)ra * lda + pa;
    const unsigned short* gb = Bp + (size_t)ra * ldb + pa;
    uint4 a0 = *(const uint4*)ga, a1 = *(const uint4*)(ga + 8);
    uint4 b0 = *(const uint4*)gb, b1 = *(const uint4*)(gb + 8);
    for (int k = 0; k < ksteps; k++) {
        __syncthreads();
        uint2* da = (uint2*)&As[ra][pa];
        da[0] = make_uint2(a0.x, a0.y); da[1] = make_uint2(a0.z, a0.w);
        da[2] = make_uint2(a1.x, a1.y); da[3] = make_uint2(a1.z, a1.w);
        uint2* db = (uint2*)&Bs[ra][pa];
        db[0] = make_uint2(b0.x, b0.y); db[1] = make_uint2(b0.z, b0.w);
        db[2] = make_uint2(b1.x, b1.y); db[3] = make_uint2(b1.z, b1.w);
        if (k + 1 < ksteps) {
            ga += 32; gb += 32;
            a0 = *(const uint4*)ga; a1 = *(const uint4*)(ga + 8);
            b0 = *(const uint4*)gb; b1 = *(const uint4*)(gb + 8);
        }
        __syncthreads();
        bf16x8 af[4], bfv[4];
        #pragma unroll
        for (int mi = 0; mi < 4; mi++) af[mi] = ld_frag(&As[rowoff + mi * 16 + fr][fq]);
        #pragma unroll
        for (int nj = 0; nj < 4; nj++) bfv[nj] = ld_frag(&Bs[coloff + nj * 16 + fr][fq]);
        #pragma unroll
        for (int mi = 0; mi < 4; mi++)
            #pragma unroll
            for (int nj = 0; nj < 4; nj++)
                acc[mi][nj] = __builtin_amdgcn_mfma_f32_16x16x32_bf16(af[mi], bfv[nj], acc[mi][nj], 0, 0, 0);
    }
}

// ---------------- head GEMM with LDS-staged coalesced epilogue ----------------
// mode 0: xb = bf16(relu(vb @ WxT[h])), AND xrb = rope(xb) fused.
// mode 1: ybf = bf16(relu(lAb @ WyT[h]) * xb), coalesced mulx reads + stores.
__global__ __launch_bounds__(256) void gemm_head_bt(const unsigned short* __restrict__ A,
                                                    const unsigned short* __restrict__ Wt,
                                                    unsigned short* __restrict__ Cx,
                                                    const unsigned short* __restrict__ mulx,
                                                    unsigned short* __restrict__ Cy,
                                                    int mode) {
    int h = blockIdx.z;
    int n0 = blockIdx.x * 128, m0 = blockIdx.y * 128;
    // 32 KB shared: As/Bs (18.4 KB) for mainloop, then re-used as Cs[128][128] bf16.
    __shared__ __attribute__((aligned(16))) unsigned short smem[16384];
    unsigned short (*As)[36] = (unsigned short (*)[36])smem;
    unsigned short (*Bs)[36] = (unsigned short (*)[36])(smem + 128 * 36);
    f32x4 acc[4][4] = {};
    bt_mainloop(A + (size_t)m0 * DD, DD,
                Wt + (size_t)h * nn * DD + (size_t)n0 * DD, DD, 8, As, Bs, acc);
    __syncthreads();   // mainloop done; smem free for output staging

    int tid = threadIdx.x, lane = tid & 63, w = tid >> 6;
    int rowoff = (w >> 1) * 64, coloff = (w & 1) * 64;
    int r4 = (lane >> 4) * 4, cc = lane & 15;
    unsigned short (*Cs)[128] = (unsigned short (*)[128])smem;
    #pragma unroll
    for (int mi = 0; mi < 4; mi++)
        #pragma unroll
        for (int nj = 0; nj < 4; nj++)
            #pragma unroll
            for (int rr = 0; rr < 4; rr++)
                Cs[rowoff + mi * 16 + r4 + rr][coloff + nj * 16 + cc] =
                    f2bf(fmaxf(acc[mi][nj][rr], 0.0f));
    __syncthreads();

    // writer arrangement: thread covers chunks {tid + j*256}, j=0..7.
    int colc = (tid & 15) * 8;
    #pragma unroll
    for (int j = 0; j < 8; j++) {
        int row = (tid >> 4) + j * 16;
        int m = m0 + row;
        int b = m >> 8, t = m & 255;
        union { uint4 u; unsigned short s[8]; } ch;
        ch.u = *(const uint4*)&Cs[row][colc];
        if (mode == 0) {
            size_t bhtn = (((size_t)(b * HH + h)) * TT + t) * (size_t)nn + n0 + colc;
            *(uint4*)(Cx + bhtn) = ch.u;                 // xb
            // fused RoPE -> xrb
            union { uint4 u; unsigned short s[8]; } ro;
            float tf = (float)t;
            int pbase = ((n0 + colc) >> 1);
            #pragma unroll
            for (int k2 = 0; k2 < 4; k2++) {
                int p = pbase + k2;
                float inv = __expf(-(float)p * (9.210340371976184f / 4096.0f));
                float ang = tf * inv;
                float s = __sinf(ang), c = __cosf(ang);
                float xe = bf2f(ch.s[2 * k2]), xo = bf2f(ch.s[2 * k2 + 1]);
                ro.s[2 * k2]     = f2bf(xe * c - xo * s);
                ro.s[2 * k2 + 1] = f2bf(xo * c + xe * s);
            }
            *(uint4*)(Cy + bhtn) = ro.u;                 // xrb
        } else {
            size_t bhtn = (((size_t)(b * HH + h)) * TT + t) * (size_t)nn + n0 + colc;
            union { uint4 u; unsigned short s[8]; } mx, oy;
            mx.u = *(const uint4*)(mulx + bhtn);
            #pragma unroll
            for (int k2 = 0; k2 < 8; k2++)
                oy.s[k2] = f2bf(bf2f(ch.s[k2]) * bf2f(mx.s[k2]));
            *(uint4*)(Cy + ((size_t)(b * TT + t)) * NN + (size_t)h * nn + n0 + colc) = oy.u;
        }
    }
}

// ---------------- scores: scp[zh][tile][kc] = partial 128x128 tile (plain stores) -----
// grid (3, SKC, BB*HH); K chunk = nn/SKC = 2048 -> 64 ksteps.
__global__ __launch_bounds__(256) void scores_bt(const unsigned short* __restrict__ xrb,
                                                 float* __restrict__ scp) {
    int zh = blockIdx.z, kc = blockIdx.y, tile = blockIdx.x;
    int t0 = (tile >= 1) ? 128 : 0;
    int s0 = (tile == 2) ? 128 : 0;
    const unsigned short* Xz = xrb + (size_t)zh * TT * nn + (size_t)kc * (nn / SKC);
    __shared__ unsigned short As[128][36], Bs[128][36];
    f32x4 acc[4][4] = {};
    bt_mainloop(Xz + (size_t)t0 * nn, nn, Xz + (size_t)s0 * nn, nn, (nn / SKC) / 32,
                As, Bs, acc);
    const float scale = 0.011048543456039805f;   // 1/sqrt(8192)
    int tid = threadIdx.x, lane = tid & 63, w = tid >> 6;
    int rowoff = (w >> 1) * 64, coloff = (w & 1) * 64;
    int r4 = (lane >> 4) * 4, cc = lane & 15;
    float* dst = scp + ((size_t)(zh * 3 + tile) * SKC + kc) * 16384;
    #pragma unroll
    for (int mi = 0; mi < 4; mi++)
        #pragma unroll
        for (int nj = 0; nj < 4; nj++)
            #pragma unroll
            for (int rr = 0; rr < 4; rr++) {
                int r = rowoff + mi * 16 + r4 + rr;
                int c = coloff + nj * 16 + cc;
                dst[r * 128 + c] = acc[mi][nj][rr] * scale;
            }
}

// ---------------- encoder GEMM: yencp[kc] = partial (plain stores) ----------
// grid (2, 4, EKC); K chunk = NN/EKC = 2048 -> 64 ksteps.
__global__ __launch_bounds__(256) void gemm_enc_bt(const unsigned short* __restrict__ A,
                                                   const unsigned short* __restrict__ Bt,
                                                   float* __restrict__ yencp) {
    int n0 = blockIdx.x * 128, m0 = blockIdx.y * 128;
    int kc = blockIdx.z;
    long kbase = (long)kc * (NN / EKC);
    __shared__ unsigned short As[128][36], Bs[128][36];
    f32x4 acc[4][4] = {};
    bt_mainloop(A + (size_t)m0 * NN + kbase, NN,
                Bt + (size_t)n0 * NN + kbase, NN, (NN / EKC) / 32, As, Bs, acc);
    int tid = threadIdx.x, lane = tid & 63, w = tid >> 6;
    int rowoff = (w >> 1) * 64, coloff = (w & 1) * 64;
    int r4 = (lane >> 4) * 4, cc = lane & 15;
    float* C = yencp + (size_t)kc * (BB * TT * DD);
    #pragma unroll
    for (int mi = 0; mi < 4; mi++)
        #pragma unroll
        for (int nj = 0; nj < 4; nj++)
            #pragma unroll
            for (int rr = 0; rr < 4; rr++) {
                int row = m0 + rowoff + mi * 16 + r4 + rr;
                int col = n0 + coloff + nj * 16 + cc;
                C[(size_t)row * DD + col] = acc[mi][nj][rr];
            }
}

// ---------------- readout: out = vb @ WroT^T, fp32 out ----------------
__global__ __launch_bounds__(256) void gemm_ro_bt(const unsigned short* __restrict__ A,
                                                  const unsigned short* __restrict__ Wt,
                                                  float* __restrict__ out) {
    int n0 = blockIdx.x * 128, m0 = blockIdx.y * 128;
    __shared__ unsigned short As[128][36], Bs[128][36];
    f32x4 acc[4][4] = {};
    bt_mainloop(A + (size_t)m0 * DD, DD, Wt + (size_t)n0 * DD, DD, 8, As, Bs, acc);
    int tid = threadIdx.x, lane = tid & 63, w = tid >> 6;
    int rowoff = (w >> 1) * 64, coloff = (w & 1) * 64;
    int r4 = (lane >> 4) * 4, cc = lane & 15;
    #pragma unroll
    for (int mi = 0; mi < 4; mi++)
        #pragma unroll
        for (int nj = 0; nj < 4; nj++)
            #pragma unroll
            for (int rr = 0; rr < 4; rr++) {
                int m = m0 + rowoff + mi * 16 + r4 + rr;
                int col = n0 + coloff + nj * 16 + cc;
                out[(size_t)m * VV + col] = acc[mi][nj][rr];
            }
}

// ---------------- causal softmax per (b,h,t) + mean over h -> am (B,T,T) --------------
// sums SKC scores partials inline (no atomics anywhere).
__global__ __launch_bounds__(256) void softmax_mean_k(const float* __restrict__ scp,
                                                      float* __restrict__ am) {
    int bt = blockIdx.x;
    int b = bt >> 8, t = bt & 255;
    int s = threadIdx.x;
    int tr = t & 127, scol = s & 127;
    int tileid = (t >= 128) ? ((s >= 128) ? 2 : 1) : 0;
    float acc = 0.0f;
    for (int h = 0; h < HH; h++) {
        int zh = b * HH + h;
        float val = -1e30f;
        if (s <= t) {
            const float* p = scp + ((size_t)(zh * 3 + tileid) * SKC) * 16384
                           + tr * 128 + scol;
            float v0 = 0.0f;
            #pragma unroll
            for (int kc = 0; kc < SKC; kc++) v0 += p[(size_t)kc * 16384];
            val = v0;
        }
        float mx = block_max(val);
        float e = (s <= t) ? expf(val - mx) : 0.0f;
        float sum = block_sum(e);
        acc += e / sum;
    }
    am[((size_t)b * TT + t) * TT + s] = acc * 0.25f;
}

// ---------------- fp32 NN GEMM — used only for a = am @ v ----------------
__global__ __launch_bounds__(256) void gemm_nn_k(const float* __restrict__ A,
                                                 const float* __restrict__ B,
                                                 float* __restrict__ C,
                                                 int M, int N, int K,
                                                 long lda, long ldb, long ldc,
                                                 long sAz, long sBz, long sCz) {
    int batch = blockIdx.z;
    A += (size_t)batch * sAz;
    B += (size_t)batch * sBz;
    C += (size_t)batch * sCz;
    int m0 = blockIdx.y * 64, n0 = blockIdx.x * 64;
    __shared__ float As[16][68];
    __shared__ float Bs[16][64];
    int tid = threadIdx.x;
    int tx = tid & 15, ty = tid >> 4;
    int ar = tid >> 2, ac = (tid & 3) * 4;
    int br = tid >> 4, bc = (tid & 15) * 4;
    float acc[4][4] = {};
    for (int k0 = 0; k0 < K; k0 += 16) {
        float4 av = *(const float4*)(A + (size_t)(m0 + ar) * lda + k0 + ac);
        float4 bv = *(const float4*)(B + (size_t)(k0 + br) * ldb + n0 + bc);
        As[ac + 0][ar] = av.x; As[ac + 1][ar] = av.y;
        As[ac + 2][ar] = av.z; As[ac + 3][ar] = av.w;
        *(float4*)&Bs[br][bc] = bv;
        __syncthreads();
        #pragma unroll
        for (int k = 0; k < 16; k++) {
            float4 a4 = *(const float4*)&As[k][ty * 4];
            float4 b4 = *(const float4*)&Bs[k][tx * 4];
            float aa[4] = {a4.x, a4.y, a4.z, a4.w};
            float bb[4] = {b4.x, b4.y, b4.z, b4.w};
            #pragma unroll
            for (int i = 0; i < 4; i++)
                #pragma unroll
                for (int j = 0; j < 4; j++)
                    acc[i][j] = fmaf(aa[i], bb[j], acc[i][j]);
        }
        __syncthreads();
    }
    #pragma unroll
    for (int i = 0; i < 4; i++) {
        int m = m0 + ty * 4 + i;
        #pragma unroll
        for (int j = 0; j < 4; j++) {
            int col = n0 + tx * 4 + j;
            C[(size_t)m * ldc + col] = acc[i][j];
        }
    }
}

// ---------------- launch ----------------
extern "C" void kernel_launch(void* const* d_in, const int* in_sizes, int n_in,
                              void* d_out, int out_size, void* d_ws, size_t ws_size,
                              hipStream_t stream) {
    const int*   idx  = (const int*)d_in[0];
    const float* wte  = (const float*)d_in[1];
    const float* enc  = (const float*)d_in[2];
    const float* Wx   = (const float*)d_in[3];
    const float* Wy   = (const float*)d_in[4];
    const float* Wro  = (const float*)d_in[5];
    float* out = (float*)d_out;

    // float region: v, am, a (512 KB each) + red (8 MB shared scratch)
    //   red serves as scp (scores partials, 6 MB, live scores->softmax)
    //   and yencp (encoder partials, 8 MB, live enc->add_ln) — disjoint lifetimes.
    float* ws   = (float*)d_ws;
    float* v    = ws;                  // 131072
    float* am   = v   + 131072;        // 131072
    float* a    = am  + 131072;        // 131072
    float* red  = a   + 131072;        // 2,097,152 floats (8 MB)
    // short region (≈118.5 MB; total ≈128.5 MB < proven 132.5 MB)
    unsigned short* sbase = (unsigned short*)(red + 2097152);
    unsigned short* vb   = sbase;                 // 131072
    unsigned short* lAb  = vb   + 131072;         // 131072
    unsigned short* xb   = lAb  + 131072;         // 16777216 (B,H,T,n); WroT aliases at end
    unsigned short* xrb  = xb   + 16777216;       // 16777216 (B,H,T,n); ybf aliases
    unsigned short* WxT  = xrb  + 16777216;       // 8388608  [h][8192][256]
    unsigned short* WyT  = WxT  + 8388608;        // 8388608
    unsigned short* encT = WyT  + 8388608;        // 8388608  [256][32768]
    unsigned short* ybf  = xrb;                   // alias: xrb dead after scores
    unsigned short* WroT = xb;                    // alias: xb dead after last y-GEMM

    // pre-pass: weight transpose+convert (once per launch, amortized over 6 layers)
    tconv_k<<<dim3(nn / 64, DD / 64, HH), 256, 0, stream>>>(Wx, WxT, DD, nn,
        (long)DD * nn, (long)nn * DD);
    tconv_k<<<dim3(DD / 64, NN / 64, 1), 256, 0, stream>>>(enc, encT, NN, DD, 0L, 0L);
    tconv_k<<<dim3(nn / 64, DD / 64, HH), 256, 0, stream>>>(Wy, WyT, DD, nn,
        (long)DD * nn, (long)nn * DD);

    // v = ln(wte[idx]) (+ bf16)
    embed_ln_k<<<BB * TT, 256, 0, stream>>>(idx, wte, v, vb);

    for (int l = 0; l < L_LAYERS; l++) {
        // xb = bf16(relu(vb @ WxT[h])), xrb = rope(xb) — fused
        gemm_head_bt<<<dim3(nn / 128, (BB * TT) / 128, HH), 256, 0, stream>>>(
            vb, WxT, xb, nullptr, xrb, 0);

        // scores partials (plain stores, no memset needed)
        scores_bt<<<dim3(3, SKC, BB * HH), 256, 0, stream>>>(xrb, red);

        // softmax (causal, sums partials) + mean over heads
        softmax_mean_k<<<BB * TT, 256, 0, stream>>>(red, am);

        // a = am @ v (per b), fp32
        gemm_nn_k<<<dim3(DD / 64, TT / 64, BB), 256, 0, stream>>>(
            am, v, a, TT, DD, TT,
            (long)TT, (long)DD, (long)DD,
            (long)TT * TT, (long)TT * DD, (long)TT * DD);

        // lAb = bf16(ln(a))
        ln_rows_k<<<BB * TT, 256, 0, stream>>>(a, lAb);

        // ybf = bf16(relu(lAb @ WyT[h]) * xb)   (ybf aliases xrb)
        gemm_head_bt<<<dim3(nn / 128, (BB * TT) / 128, HH), 256, 0, stream>>>(
            lAb, WyT, nullptr, xb, ybf, 1);

        // yencp[kc] = partial ybf @ enc (plain stores)
        gemm_enc_bt<<<dim3(2, 4, EKC), 256, 0, stream>>>(ybf, encT, red);

        // v = ln(v + ln(sum yencp)) (+ bf16)
        add_ln_ln_k<<<BB * TT, 256, 0, stream>>>(v, red, vb);
    }

    // WroT = transpose+bf16(Wro) into xb region (xb dead now)
    tconv_k<<<dim3(VV / 64, DD / 64, 1), 256, 0, stream>>>(Wro, WroT, DD, VV, 0L, 0L);

    // out = vb @ WroT^T (fp32 out)
    gemm_ro_bt<<<dim3(VV / 128, (BB * TT) / 128, 1), 256, 0, stream>>>(vb, WroT, out);
}

// Round 7
// 1004.497 us; speedup vs baseline: 1.2993x; 1.1665x over previous
//
#include <hip/hip_runtime.h>
#include <hip/hip_bf16.h>
#include <math.h>

// Problem constants
#define BB   2
#define TT   256
#define DD   256
#define HH   4
#define NN   32768
#define nn   8192
#define VV   32000
#define L_LAYERS 6
#define LN_EPS 1e-5f

#define SKC  8      // scores split-K partials (12 MB in red)
#define EKC  16     // encoder split-K partials (8 MB, aliases red)

typedef __attribute__((ext_vector_type(8))) short bf16x8;
typedef __attribute__((ext_vector_type(4))) float f32x4;

__device__ __forceinline__ unsigned short f2bf(float f) {
    union { float f; unsigned int u; } v; v.f = f;
    unsigned int r = (v.u + 0x7FFFu + ((v.u >> 16) & 1u)) >> 16;
    return (unsigned short)r;
}
__device__ __forceinline__ float bf2f(unsigned short h) {
    union { unsigned int u; float f; } v; v.u = ((unsigned int)h) << 16;
    return v.f;
}
__device__ __forceinline__ bf16x8 ld_frag(const unsigned short* p) {
    union { bf16x8 v; uint2 u[2]; } r;
    r.u[0] = *(const uint2*)(p);
    r.u[1] = *(const uint2*)(p + 4);
    return r.v;
}

// ---------------- block reduction helpers (256 threads = 4 waves) ----------------
__device__ __forceinline__ float block_sum(float v) {
    __shared__ float sh[4];
    #pragma unroll
    for (int o = 32; o > 0; o >>= 1) v += __shfl_down(v, o, 64);
    __syncthreads();
    if ((threadIdx.x & 63) == 0) sh[threadIdx.x >> 6] = v;
    __syncthreads();
    return sh[0] + sh[1] + sh[2] + sh[3];
}
__device__ __forceinline__ float block_max(float v) {
    __shared__ float sh[4];
    #pragma unroll
    for (int o = 32; o > 0; o >>= 1) v = fmaxf(v, __shfl_down(v, o, 64));
    __syncthreads();
    if ((threadIdx.x & 63) == 0) sh[threadIdx.x >> 6] = v;
    __syncthreads();
    return fmaxf(fmaxf(sh[0], sh[1]), fmaxf(sh[2], sh[3]));
}
__device__ __forceinline__ float ln_val(float x) {
    float m = block_sum(x) * (1.0f / 256.0f);
    float d = x - m;
    float var = block_sum(d * d) * (1.0f / 256.0f);
    return d * rsqrtf(var + LN_EPS);
}

// ---------------- small row kernels ----------------
__global__ __launch_bounds__(256) void embed_ln_k(const int* __restrict__ idx,
                                                  const float* __restrict__ wte,
                                                  float* __restrict__ v,
                                                  unsigned short* __restrict__ vb) {
    int row = blockIdx.x;
    int tok = idx[row];
    float x = wte[(size_t)tok * DD + threadIdx.x];
    float o = ln_val(x);
    size_t i = (size_t)row * DD + threadIdx.x;
    v[i] = o;
    vb[i] = f2bf(o);
}

__global__ __launch_bounds__(256) void ln_rows_k(const float* __restrict__ in,
                                                 unsigned short* __restrict__ ob) {
    size_t i = (size_t)blockIdx.x * DD + threadIdx.x;
    ob[i] = f2bf(ln_val(in[i]));
}

// v = ln(v + ln(sum_kc yencp)) (+ bf16)  — folds encoder split-K reduction
__global__ __launch_bounds__(256) void add_ln_ln_k(float* __restrict__ v,
                                                   const float* __restrict__ yencp,
                                                   unsigned short* __restrict__ vb) {
    size_t i = (size_t)blockIdx.x * DD + threadIdx.x;
    float ysum = 0.0f;
    #pragma unroll
    for (int kc = 0; kc < EKC; kc++)
        ysum += yencp[(size_t)kc * (BB * TT * DD) + i];
    float t1 = ln_val(ysum);
    float w = v[i] + t1;
    float o = ln_val(w);
    v[i] = o;
    vb[i] = f2bf(o);
}

// ---------------- transpose+convert: dst[c][r] bf16 = src[r][c] fp32 ----------------
__global__ __launch_bounds__(256) void tconv_k(const float* __restrict__ src,
                                               unsigned short* __restrict__ dst,
                                               int R, int C, long sstride, long dstride) {
    src += (size_t)blockIdx.z * sstride;
    dst += (size_t)blockIdx.z * dstride;
    __shared__ unsigned short tile[64][66];
    int c0 = blockIdx.x * 64, r0 = blockIdx.y * 64;
    int c = threadIdx.x & 63, q = threadIdx.x >> 6;
    #pragma unroll
    for (int i = 0; i < 16; i++) {
        int r = q + i * 4;
        tile[r][c] = f2bf(src[(size_t)(r0 + r) * C + c0 + c]);
    }
    __syncthreads();
    #pragma unroll
    for (int i = 0; i < 16; i++) {
        int r = q + i * 4;
        dst[(size_t)(c0 + r) * R + r0 + c] = tile[c][r];
    }
}

// ======================================================================
// BK=64 LDS-staged BT-GEMM mainloop (reg-staged, 1-deep prefetch).
// Same structure as the R3/R5-verified BK=32 loop, but half the k-steps
// and half the barriers (latency chain halves at identical traffic).
// Block tile 128x128; 4 waves; each wave 64x64 via 4x4 16x16x32 MFMA frags,
// two K=32 sub-slices per k-step. LDS: 2 x [128][68] shorts = 34.8 KB.
// ======================================================================
__device__ __forceinline__ void bt_mainloop64(const unsigned short* Ap, long lda,
                                              const unsigned short* Bp, long ldb,
                                              int ksteps,
                                              unsigned short (*As)[68],
                                              unsigned short (*Bs)[68],
                                              f32x4 (&acc)[4][4]) {
    int tid = threadIdx.x;
    int ra = tid >> 1, pa = (tid & 1) * 32;      // 2 threads/row, 32 cols (64 B) each
    int lane = tid & 63, w = tid >> 6;
    int rowoff = (w >> 1) * 64, coloff = (w & 1) * 64;
    int fr = lane & 15, fq = (lane >> 4) * 8;
    const unsigned short* ga = Ap + (size_t)ra * lda + pa;
    const unsigned short* gb = Bp + (size_t)ra * ldb + pa;
    uint4 a0 = *(const uint4*)ga,        a1 = *(const uint4*)(ga + 8);
    uint4 a2 = *(const uint4*)(ga + 16), a3 = *(const uint4*)(ga + 24);
    uint4 b0 = *(const uint4*)gb,        b1 = *(const uint4*)(gb + 8);
    uint4 b2 = *(const uint4*)(gb + 16), b3 = *(const uint4*)(gb + 24);
    for (int k = 0; k < ksteps; k++) {
        __syncthreads();
        uint2* da = (uint2*)&As[ra][pa];
        da[0] = make_uint2(a0.x, a0.y); da[1] = make_uint2(a0.z, a0.w);
        da[2] = make_uint2(a1.x, a1.y); da[3] = make_uint2(a1.z, a1.w);
        da[4] = make_uint2(a2.x, a2.y); da[5] = make_uint2(a2.z, a2.w);
        da[6] = make_uint2(a3.x, a3.y); da[7] = make_uint2(a3.z, a3.w);
        uint2* db = (uint2*)&Bs[ra][pa];
        db[0] = make_uint2(b0.x, b0.y); db[1] = make_uint2(b0.z, b0.w);
        db[2] = make_uint2(b1.x, b1.y); db[3] = make_uint2(b1.z, b1.w);
        db[4] = make_uint2(b2.x, b2.y); db[5] = make_uint2(b2.z, b2.w);
        db[6] = make_uint2(b3.x, b3.y); db[7] = make_uint2(b3.z, b3.w);
        if (k + 1 < ksteps) {
            ga += 64; gb += 64;
            a0 = *(const uint4*)ga;        a1 = *(const uint4*)(ga + 8);
            a2 = *(const uint4*)(ga + 16); a3 = *(const uint4*)(ga + 24);
            b0 = *(const uint4*)gb;        b1 = *(const uint4*)(gb + 8);
            b2 = *(const uint4*)(gb + 16); b3 = *(const uint4*)(gb + 24);
        }
        __syncthreads();
        #pragma unroll
        for (int ks = 0; ks < 2; ks++) {
            bf16x8 af[4], bfv[4];
            #pragma unroll
            for (int mi = 0; mi < 4; mi++)
                af[mi] = ld_frag(&As[rowoff + mi * 16 + fr][ks * 32 + fq]);
            #pragma unroll
            for (int nj = 0; nj < 4; nj++)
                bfv[nj] = ld_frag(&Bs[coloff + nj * 16 + fr][ks * 32 + fq]);
            #pragma unroll
            for (int mi = 0; mi < 4; mi++)
                #pragma unroll
                for (int nj = 0; nj < 4; nj++)
                    acc[mi][nj] = __builtin_amdgcn_mfma_f32_16x16x32_bf16(af[mi], bfv[nj], acc[mi][nj], 0, 0, 0);
        }
    }
}

// ---------------- head GEMM with LDS-staged coalesced epilogue ----------------
// mode 0: xb = bf16(relu(vb @ WxT[h])), AND xrb = rope(xb) fused.
// mode 1: ybf = bf16(relu(lAb @ WyT[h]) * xb), coalesced mulx reads + stores.
__global__ __launch_bounds__(256) void gemm_head_bt(const unsigned short* __restrict__ A,
                                                    const unsigned short* __restrict__ Wt,
                                                    unsigned short* __restrict__ Cx,
                                                    const unsigned short* __restrict__ mulx,
                                                    unsigned short* __restrict__ Cy,
                                                    int mode) {
    int h = blockIdx.z;
    int n0 = blockIdx.x * 128, m0 = blockIdx.y * 128;
    // 34.8 KB shared for mainloop (2x[128][68]); reused as Cs[128][128] (32 KB) after.
    __shared__ __attribute__((aligned(16))) unsigned short smem[17408];
    unsigned short (*As)[68] = (unsigned short (*)[68])smem;
    unsigned short (*Bs)[68] = (unsigned short (*)[68])(smem + 8704);
    f32x4 acc[4][4] = {};
    bt_mainloop64(A + (size_t)m0 * DD, DD,
                  Wt + (size_t)h * nn * DD + (size_t)n0 * DD, DD, 4, As, Bs, acc);
    __syncthreads();   // mainloop done; smem free for output staging

    int tid = threadIdx.x, lane = tid & 63, w = tid >> 6;
    int rowoff = (w >> 1) * 64, coloff = (w & 1) * 64;
    int r4 = (lane >> 4) * 4, cc = lane & 15;
    unsigned short (*Cs)[128] = (unsigned short (*)[128])smem;
    #pragma unroll
    for (int mi = 0; mi < 4; mi++)
        #pragma unroll
        for (int nj = 0; nj < 4; nj++)
            #pragma unroll
            for (int rr = 0; rr < 4; rr++)
                Cs[rowoff + mi * 16 + r4 + rr][coloff + nj * 16 + cc] =
                    f2bf(fmaxf(acc[mi][nj][rr], 0.0f));
    __syncthreads();

    // writer arrangement: thread covers chunks {tid + j*256}, j=0..7 (16 B / chunk).
    int colc = (tid & 15) * 8;
    #pragma unroll
    for (int j = 0; j < 8; j++) {
        int row = (tid >> 4) + j * 16;
        int m = m0 + row;
        int b = m >> 8, t = m & 255;
        union { uint4 u; unsigned short s[8]; } ch;
        ch.u = *(const uint4*)&Cs[row][colc];
        size_t bhtn = (((size_t)(b * HH + h)) * TT + t) * (size_t)nn + n0 + colc;
        if (mode == 0) {
            *(uint4*)(Cx + bhtn) = ch.u;                 // xb
            // fused RoPE -> xrb
            union { uint4 u; unsigned short s[8]; } ro;
            float tf = (float)t;
            int pbase = ((n0 + colc) >> 1);
            #pragma unroll
            for (int k2 = 0; k2 < 4; k2++) {
                int p = pbase + k2;
                float inv = __expf(-(float)p * (9.210340371976184f / 4096.0f));
                float ang = tf * inv;
                float s = __sinf(ang), c = __cosf(ang);
                float xe = bf2f(ch.s[2 * k2]), xo = bf2f(ch.s[2 * k2 + 1]);
                ro.s[2 * k2]     = f2bf(xe * c - xo * s);
                ro.s[2 * k2 + 1] = f2bf(xo * c + xe * s);
            }
            *(uint4*)(Cy + bhtn) = ro.u;                 // xrb
        } else {
            union { uint4 u; unsigned short s[8]; } mx, oy;
            mx.u = *(const uint4*)(mulx + bhtn);
            #pragma unroll
            for (int k2 = 0; k2 < 8; k2++)
                oy.s[k2] = f2bf(bf2f(ch.s[k2]) * bf2f(mx.s[k2]));
            *(uint4*)(Cy + ((size_t)(b * TT + t)) * NN + (size_t)h * nn + n0 + colc) = oy.u;
        }
    }
}

// ---------------- scores: scp[zh][tile][kc] = partial 128x128 tile (plain stores) -----
// grid (3, SKC, BB*HH); K chunk = nn/SKC = 1024 -> 16 ksteps of BK=64.
__global__ __launch_bounds__(256) void scores_bt(const unsigned short* __restrict__ xrb,
                                                 float* __restrict__ scp) {
    int zh = blockIdx.z, kc = blockIdx.y, tile = blockIdx.x;
    int t0 = (tile >= 1) ? 128 : 0;
    int s0 = (tile == 2) ? 128 : 0;
    const unsigned short* Xz = xrb + (size_t)zh * TT * nn + (size_t)kc * (nn / SKC);
    __shared__ __attribute__((aligned(16))) unsigned short As[128][68], Bs[128][68];
    f32x4 acc[4][4] = {};
    bt_mainloop64(Xz + (size_t)t0 * nn, nn, Xz + (size_t)s0 * nn, nn, (nn / SKC) / 64,
                  As, Bs, acc);
    const float scale = 0.011048543456039805f;   // 1/sqrt(8192)
    int tid = threadIdx.x, lane = tid & 63, w = tid >> 6;
    int rowoff = (w >> 1) * 64, coloff = (w & 1) * 64;
    int r4 = (lane >> 4) * 4, cc = lane & 15;
    float* dst = scp + ((size_t)(zh * 3 + tile) * SKC + kc) * 16384;
    #pragma unroll
    for (int mi = 0; mi < 4; mi++)
        #pragma unroll
        for (int nj = 0; nj < 4; nj++)
            #pragma unroll
            for (int rr = 0; rr < 4; rr++) {
                int r = rowoff + mi * 16 + r4 + rr;
                int c = coloff + nj * 16 + cc;
                dst[r * 128 + c] = acc[mi][nj][rr] * scale;
            }
}

// ---------------- encoder GEMM: yencp[kc] = partial (plain stores) ----------
// grid (2, 4, EKC); K chunk = NN/EKC = 2048 -> 32 ksteps of BK=64.
__global__ __launch_bounds__(256) void gemm_enc_bt(const unsigned short* __restrict__ A,
                                                   const unsigned short* __restrict__ Bt,
                                                   float* __restrict__ yencp) {
    int n0 = blockIdx.x * 128, m0 = blockIdx.y * 128;
    int kc = blockIdx.z;
    long kbase = (long)kc * (NN / EKC);
    __shared__ __attribute__((aligned(16))) unsigned short As[128][68], Bs[128][68];
    f32x4 acc[4][4] = {};
    bt_mainloop64(A + (size_t)m0 * NN + kbase, NN,
                  Bt + (size_t)n0 * NN + kbase, NN, (NN / EKC) / 64, As, Bs, acc);
    int tid = threadIdx.x, lane = tid & 63, w = tid >> 6;
    int rowoff = (w >> 1) * 64, coloff = (w & 1) * 64;
    int r4 = (lane >> 4) * 4, cc = lane & 15;
    float* C = yencp + (size_t)kc * (BB * TT * DD);
    #pragma unroll
    for (int mi = 0; mi < 4; mi++)
        #pragma unroll
        for (int nj = 0; nj < 4; nj++)
            #pragma unroll
            for (int rr = 0; rr < 4; rr++) {
                int row = m0 + rowoff + mi * 16 + r4 + rr;
                int col = n0 + coloff + nj * 16 + cc;
                C[(size_t)row * DD + col] = acc[mi][nj][rr];
            }
}

// ---------------- readout: out = vb @ WroT^T, fp32 out ----------------
__global__ __launch_bounds__(256) void gemm_ro_bt(const unsigned short* __restrict__ A,
                                                  const unsigned short* __restrict__ Wt,
                                                  float* __restrict__ out) {
    int n0 = blockIdx.x * 128, m0 = blockIdx.y * 128;
    __shared__ __attribute__((aligned(16))) unsigned short As[128][68], Bs[128][68];
    f32x4 acc[4][4] = {};
    bt_mainloop64(A + (size_t)m0 * DD, DD, Wt + (size_t)n0 * DD, DD, 4, As, Bs, acc);
    int tid = threadIdx.x, lane = tid & 63, w = tid >> 6;
    int rowoff = (w >> 1) * 64, coloff = (w & 1) * 64;
    int r4 = (lane >> 4) * 4, cc = lane & 15;
    #pragma unroll
    for (int mi = 0; mi < 4; mi++)
        #pragma unroll
        for (int nj = 0; nj < 4; nj++)
            #pragma unroll
            for (int rr = 0; rr < 4; rr++) {
                int m = m0 + rowoff + mi * 16 + r4 + rr;
                int col = n0 + coloff + nj * 16 + cc;
                out[(size_t)m * VV + col] = acc[mi][nj][rr];
            }
}

// ---------------- causal softmax per (b,h,t) + mean over h -> am (B,T,T) --------------
// sums SKC scores partials inline (no atomics anywhere).
__global__ __launch_bounds__(256) void softmax_mean_k(const float* __restrict__ scp,
                                                      float* __restrict__ am) {
    int bt = blockIdx.x;
    int b = bt >> 8, t = bt & 255;
    int s = threadIdx.x;
    int tr = t & 127, scol = s & 127;
    int tileid = (t >= 128) ? ((s >= 128) ? 2 : 1) : 0;
    float acc = 0.0f;
    for (int h = 0; h < HH; h++) {
        int zh = b * HH + h;
        float val = -1e30f;
        if (s <= t) {
            const float* p = scp + ((size_t)(zh * 3 + tileid) * SKC) * 16384
                           + tr * 128 + scol;
            float v0 = 0.0f;
            #pragma unroll
            for (int kc = 0; kc < SKC; kc++) v0 += p[(size_t)kc * 16384];
            val = v0;
        }
        float mx = block_max(val);
        float e = (s <= t) ? expf(val - mx) : 0.0f;
        float sum = block_sum(e);
        acc += e / sum;
    }
    am[((size_t)b * TT + t) * TT + s] = acc * 0.25f;
}

// ---------------- fp32 NN GEMM — used only for a = am @ v ----------------
__global__ __launch_bounds__(256) void gemm_nn_k(const float* __restrict__ A,
                                                 const float* __restrict__ B,
                                                 float* __restrict__ C,
                                                 int M, int N, int K,
                                                 long lda, long ldb, long ldc,
                                                 long sAz, long sBz, long sCz) {
    int batch = blockIdx.z;
    A += (size_t)batch * sAz;
    B += (size_t)batch * sBz;
    C += (size_t)batch * sCz;
    int m0 = blockIdx.y * 64, n0 = blockIdx.x * 64;
    __shared__ float As[16][68];
    __shared__ float Bs[16][64];
    int tid = threadIdx.x;
    int tx = tid & 15, ty = tid >> 4;
    int ar = tid >> 2, ac = (tid & 3) * 4;
    int br = tid >> 4, bc = (tid & 15) * 4;
    float acc[4][4] = {};
    for (int k0 = 0; k0 < K; k0 += 16) {
        float4 av = *(const float4*)(A + (size_t)(m0 + ar) * lda + k0 + ac);
        float4 bv = *(const float4*)(B + (size_t)(k0 + br) * ldb + n0 + bc);
        As[ac + 0][ar] = av.x; As[ac + 1][ar] = av.y;
        As[ac + 2][ar] = av.z; As[ac + 3][ar] = av.w;
        *(float4*)&Bs[br][bc] = bv;
        __syncthreads();
        #pragma unroll
        for (int k = 0; k < 16; k++) {
            float4 a4 = *(const float4*)&As[k][ty * 4];
            float4 b4 = *(const float4*)&Bs[k][tx * 4];
            float aa[4] = {a4.x, a4.y, a4.z, a4.w};
            float bb[4] = {b4.x, b4.y, b4.z, b4.w};
            #pragma unroll
            for (int i = 0; i < 4; i++)
                #pragma unroll
                for (int j = 0; j < 4; j++)
                    acc[i][j] = fmaf(aa[i], bb[j], acc[i][j]);
        }
        __syncthreads();
    }
    #pragma unroll
    for (int i = 0; i < 4; i++) {
        int m = m0 + ty * 4 + i;
        #pragma unroll
        for (int j = 0; j < 4; j++) {
            int col = n0 + tx * 4 + j;
            C[(size_t)m * ldc + col] = acc[i][j];
        }
    }
}

// ---------------- launch ----------------
extern "C" void kernel_launch(void* const* d_in, const int* in_sizes, int n_in,
                              void* d_out, int out_size, void* d_ws, size_t ws_size,
                              hipStream_t stream) {
    const int*   idx  = (const int*)d_in[0];
    const float* wte  = (const float*)d_in[1];
    const float* enc  = (const float*)d_in[2];
    const float* Wx   = (const float*)d_in[3];
    const float* Wy   = (const float*)d_in[4];
    const float* Wro  = (const float*)d_in[5];
    float* out = (float*)d_out;

    // float region: v, am, a (512 KB each) + red (12 MB shared scratch)
    //   red serves as scp (scores partials, 12 MB, live scores->softmax)
    //   and yencp (encoder partials, 8 MB, live enc->add_ln) — disjoint lifetimes.
    float* ws   = (float*)d_ws;
    float* v    = ws;                  // 131072
    float* am   = v   + 131072;        // 131072
    float* a    = am  + 131072;        // 131072
    float* red  = a   + 131072;        // 3,145,728 floats (12 MB)
    // short region (112.5 MB; total 126.0 MB < proven 132.5 MB)
    unsigned short* sbase = (unsigned short*)(red + 3145728);
    unsigned short* vb   = sbase;                 // 131072
    unsigned short* lAb  = vb   + 131072;         // 131072
    unsigned short* xb   = lAb  + 131072;         // 16777216 (B,H,T,n); WroT aliases at end
    unsigned short* xrb  = xb   + 16777216;       // 16777216 (B,H,T,n); ybf aliases
    unsigned short* WxT  = xrb  + 16777216;       // 8388608  [h][8192][256]
    unsigned short* WyT  = WxT  + 8388608;        // 8388608
    unsigned short* encT = WyT  + 8388608;        // 8388608  [256][32768]
    unsigned short* ybf  = xrb;                   // alias: xrb dead after scores
    unsigned short* WroT = xb;                    // alias: xb dead after last y-GEMM
    float* yencp = red;                           // alias: scp dead after softmax

    // pre-pass: weight transpose+convert (once per launch, amortized over 6 layers)
    tconv_k<<<dim3(nn / 64, DD / 64, HH), 256, 0, stream>>>(Wx, WxT, DD, nn,
        (long)DD * nn, (long)nn * DD);
    tconv_k<<<dim3(DD / 64, NN / 64, 1), 256, 0, stream>>>(enc, encT, NN, DD, 0L, 0L);
    tconv_k<<<dim3(nn / 64, DD / 64, HH), 256, 0, stream>>>(Wy, WyT, DD, nn,
        (long)DD * nn, (long)nn * DD);

    // v = ln(wte[idx]) (+ bf16)
    embed_ln_k<<<BB * TT, 256, 0, stream>>>(idx, wte, v, vb);

    for (int l = 0; l < L_LAYERS; l++) {
        // xb = bf16(relu(vb @ WxT[h])), xrb = rope(xb) — fused
        gemm_head_bt<<<dim3(nn / 128, (BB * TT) / 128, HH), 256, 0, stream>>>(
            vb, WxT, xb, nullptr, xrb, 0);

        // scores partials (plain stores, no memset, no atomics)
        scores_bt<<<dim3(3, SKC, BB * HH), 256, 0, stream>>>(xrb, red);

        // softmax (causal, sums partials) + mean over heads
        softmax_mean_k<<<BB * TT, 256, 0, stream>>>(red, am);

        // a = am @ v (per b), fp32
        gemm_nn_k<<<dim3(DD / 64, TT / 64, BB), 256, 0, stream>>>(
            am, v, a, TT, DD, TT,
            (long)TT, (long)DD, (long)DD,
            (long)TT * TT, (long)TT * DD, (long)TT * DD);

        // lAb = bf16(ln(a))
        ln_rows_k<<<BB * TT, 256, 0, stream>>>(a, lAb);

        // ybf = bf16(relu(lAb @ WyT[h]) * xb)   (ybf aliases xrb — xrb dead)
        gemm_head_bt<<<dim3(nn / 128, (BB * TT) / 128, HH), 256, 0, stream>>>(
            lAb, WyT, nullptr, xb, ybf, 1);

        // yencp[kc] = partial ybf @ enc (plain stores into red — scp dead)
        gemm_enc_bt<<<dim3(2, 4, EKC), 256, 0, stream>>>(ybf, encT, yencp);

        // v = ln(v + ln(sum yencp)) (+ bf16)
        add_ln_ln_k<<<BB * TT, 256, 0, stream>>>(v, yencp, vb);
    }

    // WroT = transpose+bf16(Wro) into xb region (xb dead now)
    tconv_k<<<dim3(VV / 64, DD / 64, 1), 256, 0, stream>>>(Wro, WroT, DD, VV, 0L, 0L);

    // out = vb @ WroT^T (fp32 out)
    gemm_ro_bt<<<dim3(VV / 128, (BB * TT) / 128, 1), 256, 0, stream>>>(vb, WroT, out);
}

// Round 8
// 937.281 us; speedup vs baseline: 1.3925x; 1.0717x over previous
//
#include <hip/hip_runtime.h>
#include <hip/hip_bf16.h>
#include <math.h>

// Problem constants
#define BB   2
#define TT   256
#define DD   256
#define HH   4
#define NN   32768
#define nn   8192
#define VV   32000
#define L_LAYERS 6
#define LN_EPS 1e-5f

#define SKC  8      // scores split-K partials (12 MB in red)
#define EKC  32     // encoder split-K partials (16 MB, aliases xrb region)

typedef __attribute__((ext_vector_type(8))) short bf16x8;
typedef __attribute__((ext_vector_type(4))) float f32x4;

__device__ __forceinline__ unsigned short f2bf(float f) {
    union { float f; unsigned int u; } v; v.f = f;
    unsigned int r = (v.u + 0x7FFFu + ((v.u >> 16) & 1u)) >> 16;
    return (unsigned short)r;
}
__device__ __forceinline__ float bf2f(unsigned short h) {
    union { unsigned int u; float f; } v; v.u = ((unsigned int)h) << 16;
    return v.f;
}
__device__ __forceinline__ bf16x8 ld_frag(const unsigned short* p) {
    union { bf16x8 v; uint2 u[2]; } r;
    r.u[0] = *(const uint2*)(p);
    r.u[1] = *(const uint2*)(p + 4);
    return r.v;
}

// ---------------- block reduction helpers (256 threads = 4 waves) ----------------
__device__ __forceinline__ float block_sum(float v) {
    __shared__ float sh[4];
    #pragma unroll
    for (int o = 32; o > 0; o >>= 1) v += __shfl_down(v, o, 64);
    __syncthreads();
    if ((threadIdx.x & 63) == 0) sh[threadIdx.x >> 6] = v;
    __syncthreads();
    return sh[0] + sh[1] + sh[2] + sh[3];
}
__device__ __forceinline__ float block_max(float v) {
    __shared__ float sh[4];
    #pragma unroll
    for (int o = 32; o > 0; o >>= 1) v = fmaxf(v, __shfl_down(v, o, 64));
    __syncthreads();
    if ((threadIdx.x & 63) == 0) sh[threadIdx.x >> 6] = v;
    __syncthreads();
    return fmaxf(fmaxf(sh[0], sh[1]), fmaxf(sh[2], sh[3]));
}
__device__ __forceinline__ float ln_val(float x) {
    float m = block_sum(x) * (1.0f / 256.0f);
    float d = x - m;
    float var = block_sum(d * d) * (1.0f / 256.0f);
    return d * rsqrtf(var + LN_EPS);
}

// ---------------- small row kernels ----------------
__global__ __launch_bounds__(256) void embed_ln_k(const int* __restrict__ idx,
                                                  const float* __restrict__ wte,
                                                  float* __restrict__ v,
                                                  unsigned short* __restrict__ vb) {
    int row = blockIdx.x;
    int tok = idx[row];
    float x = wte[(size_t)tok * DD + threadIdx.x];
    float o = ln_val(x);
    size_t i = (size_t)row * DD + threadIdx.x;
    v[i] = o;
    vb[i] = f2bf(o);
}

__global__ __launch_bounds__(256) void ln_rows_k(const float* __restrict__ in,
                                                 unsigned short* __restrict__ ob) {
    size_t i = (size_t)blockIdx.x * DD + threadIdx.x;
    ob[i] = f2bf(ln_val(in[i]));
}

// v = ln(v + ln(sum_kc yencp)) (+ bf16)  — folds encoder split-K reduction
__global__ __launch_bounds__(256) void add_ln_ln_k(float* __restrict__ v,
                                                   const float* __restrict__ yencp,
                                                   unsigned short* __restrict__ vb) {
    size_t i = (size_t)blockIdx.x * DD + threadIdx.x;
    float ysum = 0.0f;
    #pragma unroll
    for (int kc = 0; kc < EKC; kc++)
        ysum += yencp[(size_t)kc * (BB * TT * DD) + i];
    float t1 = ln_val(ysum);
    float w = v[i] + t1;
    float o = ln_val(w);
    v[i] = o;
    vb[i] = f2bf(o);
}

// ---------------- transpose+convert: dst[c][r] bf16 = src[r][c] fp32 ----------------
__global__ __launch_bounds__(256) void tconv_k(const float* __restrict__ src,
                                               unsigned short* __restrict__ dst,
                                               int R, int C, long sstride, long dstride) {
    src += (size_t)blockIdx.z * sstride;
    dst += (size_t)blockIdx.z * dstride;
    __shared__ unsigned short tile[64][66];
    int c0 = blockIdx.x * 64, r0 = blockIdx.y * 64;
    int c = threadIdx.x & 63, q = threadIdx.x >> 6;
    #pragma unroll
    for (int i = 0; i < 16; i++) {
        int r = q + i * 4;
        tile[r][c] = f2bf(src[(size_t)(r0 + r) * C + c0 + c]);
    }
    __syncthreads();
    #pragma unroll
    for (int i = 0; i < 16; i++) {
        int r = q + i * 4;
        dst[(size_t)(c0 + r) * R + r0 + c] = tile[c][r];
    }
}

// ======================================================================
// BK=64 LDS-staged BT-GEMM mainloop (reg-staged, 1-deep prefetch).
// R7-verified: halved k-steps/barriers vs BK=32 gave −14% end-to-end.
// Block tile 128x128; 4 waves; each wave 64x64 via 4x4 16x16x32 MFMA frags,
// two K=32 sub-slices per k-step. LDS: 2 x [128][68] shorts = 34.8 KB.
// ======================================================================
__device__ __forceinline__ void bt_mainloop64(const unsigned short* Ap, long lda,
                                              const unsigned short* Bp, long ldb,
                                              int ksteps,
                                              unsigned short (*As)[68],
                                              unsigned short (*Bs)[68],
                                              f32x4 (&acc)[4][4]) {
    int tid = threadIdx.x;
    int ra = tid >> 1, pa = (tid & 1) * 32;      // 2 threads/row, 32 cols (64 B) each
    int lane = tid & 63, w = tid >> 6;
    int rowoff = (w >> 1) * 64, coloff = (w & 1) * 64;
    int fr = lane & 15, fq = (lane >> 4) * 8;
    const unsigned short* ga = Ap + (size_t)ra * lda + pa;
    const unsigned short* gb = Bp + (size_t)ra * ldb + pa;
    uint4 a0 = *(const uint4*)ga,        a1 = *(const uint4*)(ga + 8);
    uint4 a2 = *(const uint4*)(ga + 16), a3 = *(const uint4*)(ga + 24);
    uint4 b0 = *(const uint4*)gb,        b1 = *(const uint4*)(gb + 8);
    uint4 b2 = *(const uint4*)(gb + 16), b3 = *(const uint4*)(gb + 24);
    for (int k = 0; k < ksteps; k++) {
        __syncthreads();
        uint2* da = (uint2*)&As[ra][pa];
        da[0] = make_uint2(a0.x, a0.y); da[1] = make_uint2(a0.z, a0.w);
        da[2] = make_uint2(a1.x, a1.y); da[3] = make_uint2(a1.z, a1.w);
        da[4] = make_uint2(a2.x, a2.y); da[5] = make_uint2(a2.z, a2.w);
        da[6] = make_uint2(a3.x, a3.y); da[7] = make_uint2(a3.z, a3.w);
        uint2* db = (uint2*)&Bs[ra][pa];
        db[0] = make_uint2(b0.x, b0.y); db[1] = make_uint2(b0.z, b0.w);
        db[2] = make_uint2(b1.x, b1.y); db[3] = make_uint2(b1.z, b1.w);
        db[4] = make_uint2(b2.x, b2.y); db[5] = make_uint2(b2.z, b2.w);
        db[6] = make_uint2(b3.x, b3.y); db[7] = make_uint2(b3.z, b3.w);
        if (k + 1 < ksteps) {
            ga += 64; gb += 64;
            a0 = *(const uint4*)ga;        a1 = *(const uint4*)(ga + 8);
            a2 = *(const uint4*)(ga + 16); a3 = *(const uint4*)(ga + 24);
            b0 = *(const uint4*)gb;        b1 = *(const uint4*)(gb + 8);
            b2 = *(const uint4*)(gb + 16); b3 = *(const uint4*)(gb + 24);
        }
        __syncthreads();
        #pragma unroll
        for (int ks = 0; ks < 2; ks++) {
            bf16x8 af[4], bfv[4];
            #pragma unroll
            for (int mi = 0; mi < 4; mi++)
                af[mi] = ld_frag(&As[rowoff + mi * 16 + fr][ks * 32 + fq]);
            #pragma unroll
            for (int nj = 0; nj < 4; nj++)
                bfv[nj] = ld_frag(&Bs[coloff + nj * 16 + fr][ks * 32 + fq]);
            #pragma unroll
            for (int mi = 0; mi < 4; mi++)
                #pragma unroll
                for (int nj = 0; nj < 4; nj++)
                    acc[mi][nj] = __builtin_amdgcn_mfma_f32_16x16x32_bf16(af[mi], bfv[nj], acc[mi][nj], 0, 0, 0);
        }
    }
}

// ---------------- head GEMM with LDS-staged coalesced epilogue ----------------
// mode 0: xrb = rope(bf16(relu(vb @ WxT[h])))  — xb never materialized.
// mode 1: ybf = bf16(relu(lAb @ WyT[h]) * inv_rope(xrb)) — x reconstructed from xrb
//         (RoPE is orthogonal; saves the 33.5 MB xb store per layer).
__global__ __launch_bounds__(256) void gemm_head_bt(const unsigned short* __restrict__ A,
                                                    const unsigned short* __restrict__ Wt,
                                                    const unsigned short* __restrict__ xr,
                                                    unsigned short* __restrict__ Cy,
                                                    int mode) {
    int h = blockIdx.z;
    int n0 = blockIdx.x * 128, m0 = blockIdx.y * 128;
    // 34.8 KB shared for mainloop (2x[128][68]); reused as Cs[128][128] (32 KB) after.
    __shared__ __attribute__((aligned(16))) unsigned short smem[17408];
    unsigned short (*As)[68] = (unsigned short (*)[68])smem;
    unsigned short (*Bs)[68] = (unsigned short (*)[68])(smem + 8704);
    f32x4 acc[4][4] = {};
    bt_mainloop64(A + (size_t)m0 * DD, DD,
                  Wt + (size_t)h * nn * DD + (size_t)n0 * DD, DD, 4, As, Bs, acc);
    __syncthreads();   // mainloop done; smem free for output staging

    int tid = threadIdx.x, lane = tid & 63, w = tid >> 6;
    int rowoff = (w >> 1) * 64, coloff = (w & 1) * 64;
    int r4 = (lane >> 4) * 4, cc = lane & 15;
    unsigned short (*Cs)[128] = (unsigned short (*)[128])smem;
    #pragma unroll
    for (int mi = 0; mi < 4; mi++)
        #pragma unroll
        for (int nj = 0; nj < 4; nj++)
            #pragma unroll
            for (int rr = 0; rr < 4; rr++)
                Cs[rowoff + mi * 16 + r4 + rr][coloff + nj * 16 + cc] =
                    f2bf(fmaxf(acc[mi][nj][rr], 0.0f));
    __syncthreads();

    // writer arrangement: thread covers chunks {tid + j*256}, j=0..7 (16 B / chunk).
    int colc = (tid & 15) * 8;
    #pragma unroll
    for (int j = 0; j < 8; j++) {
        int row = (tid >> 4) + j * 16;
        int m = m0 + row;
        int b = m >> 8, t = m & 255;
        union { uint4 u; unsigned short s[8]; } ch;
        ch.u = *(const uint4*)&Cs[row][colc];
        size_t bhtn = (((size_t)(b * HH + h)) * TT + t) * (size_t)nn + n0 + colc;
        float tf = (float)t;
        int pbase = ((n0 + colc) >> 1);
        if (mode == 0) {
            // RoPE forward -> xrb (only output)
            union { uint4 u; unsigned short s[8]; } ro;
            #pragma unroll
            for (int k2 = 0; k2 < 4; k2++) {
                int p = pbase + k2;
                float inv = __expf(-(float)p * (9.210340371976184f / 4096.0f));
                float ang = tf * inv;
                float s = __sinf(ang), c = __cosf(ang);
                float xe = bf2f(ch.s[2 * k2]), xo = bf2f(ch.s[2 * k2 + 1]);
                ro.s[2 * k2]     = f2bf(xe * c - xo * s);
                ro.s[2 * k2 + 1] = f2bf(xo * c + xe * s);
            }
            *(uint4*)(Cy + bhtn) = ro.u;                 // xrb
        } else {
            // reconstruct x = inv_rope(xrb) and multiply
            union { uint4 u; unsigned short s[8]; } xu, oy;
            xu.u = *(const uint4*)(xr + bhtn);
            #pragma unroll
            for (int k2 = 0; k2 < 4; k2++) {
                int p = pbase + k2;
                float inv = __expf(-(float)p * (9.210340371976184f / 4096.0f));
                float ang = tf * inv;
                float s = __sinf(ang), c = __cosf(ang);
                float oe = bf2f(xu.s[2 * k2]), oo = bf2f(xu.s[2 * k2 + 1]);
                float xe = oe * c + oo * s;              // inverse rotation
                float xo = oo * c - oe * s;
                oy.s[2 * k2]     = f2bf(bf2f(ch.s[2 * k2])     * xe);
                oy.s[2 * k2 + 1] = f2bf(bf2f(ch.s[2 * k2 + 1]) * xo);
            }
            *(uint4*)(Cy + ((size_t)(b * TT + t)) * NN + (size_t)h * nn + n0 + colc) = oy.u;
        }
    }
}

// ---------------- scores: scp[zh][tile][kc] = partial 128x128 tile (plain stores) -----
// grid (3, SKC, BB*HH); K chunk = nn/SKC = 1024 -> 16 ksteps of BK=64.
__global__ __launch_bounds__(256) void scores_bt(const unsigned short* __restrict__ xrb,
                                                 float* __restrict__ scp) {
    int zh = blockIdx.z, kc = blockIdx.y, tile = blockIdx.x;
    int t0 = (tile >= 1) ? 128 : 0;
    int s0 = (tile == 2) ? 128 : 0;
    const unsigned short* Xz = xrb + (size_t)zh * TT * nn + (size_t)kc * (nn / SKC);
    __shared__ __attribute__((aligned(16))) unsigned short As[128][68], Bs[128][68];
    f32x4 acc[4][4] = {};
    bt_mainloop64(Xz + (size_t)t0 * nn, nn, Xz + (size_t)s0 * nn, nn, (nn / SKC) / 64,
                  As, Bs, acc);
    const float scale = 0.011048543456039805f;   // 1/sqrt(8192)
    int tid = threadIdx.x, lane = tid & 63, w = tid >> 6;
    int rowoff = (w >> 1) * 64, coloff = (w & 1) * 64;
    int r4 = (lane >> 4) * 4, cc = lane & 15;
    float* dst = scp + ((size_t)(zh * 3 + tile) * SKC + kc) * 16384;
    #pragma unroll
    for (int mi = 0; mi < 4; mi++)
        #pragma unroll
        for (int nj = 0; nj < 4; nj++)
            #pragma unroll
            for (int rr = 0; rr < 4; rr++) {
                int r = rowoff + mi * 16 + r4 + rr;
                int c = coloff + nj * 16 + cc;
                dst[r * 128 + c] = acc[mi][nj][rr] * scale;
            }
}

// ---------------- encoder GEMM: yencp[kc] = partial (plain stores) ----------
// grid (2, 4, EKC); K chunk = NN/EKC = 1024 -> 16 ksteps of BK=64; 256 blocks = 1/CU.
__global__ __launch_bounds__(256) void gemm_enc_bt(const unsigned short* __restrict__ A,
                                                   const unsigned short* __restrict__ Bt,
                                                   float* __restrict__ yencp) {
    int n0 = blockIdx.x * 128, m0 = blockIdx.y * 128;
    int kc = blockIdx.z;
    long kbase = (long)kc * (NN / EKC);
    __shared__ __attribute__((aligned(16))) unsigned short As[128][68], Bs[128][68];
    f32x4 acc[4][4] = {};
    bt_mainloop64(A + (size_t)m0 * NN + kbase, NN,
                  Bt + (size_t)n0 * NN + kbase, NN, (NN / EKC) / 64, As, Bs, acc);
    int tid = threadIdx.x, lane = tid & 63, w = tid >> 6;
    int rowoff = (w >> 1) * 64, coloff = (w & 1) * 64;
    int r4 = (lane >> 4) * 4, cc = lane & 15;
    float* C = yencp + (size_t)kc * (BB * TT * DD);
    #pragma unroll
    for (int mi = 0; mi < 4; mi++)
        #pragma unroll
        for (int nj = 0; nj < 4; nj++)
            #pragma unroll
            for (int rr = 0; rr < 4; rr++) {
                int row = m0 + rowoff + mi * 16 + r4 + rr;
                int col = n0 + coloff + nj * 16 + cc;
                C[(size_t)row * DD + col] = acc[mi][nj][rr];
            }
}

// ---------------- readout: out = vb @ WroT^T, fp32 out ----------------
__global__ __launch_bounds__(256) void gemm_ro_bt(const unsigned short* __restrict__ A,
                                                  const unsigned short* __restrict__ Wt,
                                                  float* __restrict__ out) {
    int n0 = blockIdx.x * 128, m0 = blockIdx.y * 128;
    __shared__ __attribute__((aligned(16))) unsigned short As[128][68], Bs[128][68];
    f32x4 acc[4][4] = {};
    bt_mainloop64(A + (size_t)m0 * DD, DD, Wt + (size_t)n0 * DD, DD, 4, As, Bs, acc);
    int tid = threadIdx.x, lane = tid & 63, w = tid >> 6;
    int rowoff = (w >> 1) * 64, coloff = (w & 1) * 64;
    int r4 = (lane >> 4) * 4, cc = lane & 15;
    #pragma unroll
    for (int mi = 0; mi < 4; mi++)
        #pragma unroll
        for (int nj = 0; nj < 4; nj++)
            #pragma unroll
            for (int rr = 0; rr < 4; rr++) {
                int m = m0 + rowoff + mi * 16 + r4 + rr;
                int col = n0 + coloff + nj * 16 + cc;
                out[(size_t)m * VV + col] = acc[mi][nj][rr];
            }
}

// ---------------- causal softmax per (b,h,t) + mean over h -> am (B,T,T) --------------
// sums SKC scores partials inline; all 4 heads batched through ONE butterfly pass
// (2 barriers total instead of 16).
__global__ __launch_bounds__(256) void softmax_mean_k(const float* __restrict__ scp,
                                                      float* __restrict__ am) {
    int bt = blockIdx.x;
    int b = bt >> 8, t = bt & 255;
    int s = threadIdx.x;
    int lane = s & 63, wid = s >> 6;
    int tr = t & 127, scol = s & 127;
    int tileid = (t >= 128) ? ((s >= 128) ? 2 : 1) : 0;
    float val[HH];
    #pragma unroll
    for (int h = 0; h < HH; h++) {
        int zh = b * HH + h;
        float v0 = -1e30f;
        if (s <= t) {
            const float* p = scp + ((size_t)(zh * 3 + tileid) * SKC) * 16384
                           + tr * 128 + scol;
            v0 = 0.0f;
            #pragma unroll
            for (int kc = 0; kc < SKC; kc++) v0 += p[(size_t)kc * 16384];
        }
        val[h] = v0;
    }
    // batched block max (4 heads in one butterfly)
    __shared__ float smx[4][4], ssm[4][4];
    float m0 = val[0], m1 = val[1], m2 = val[2], m3 = val[3];
    #pragma unroll
    for (int o = 32; o > 0; o >>= 1) {
        m0 = fmaxf(m0, __shfl_down(m0, o, 64));
        m1 = fmaxf(m1, __shfl_down(m1, o, 64));
        m2 = fmaxf(m2, __shfl_down(m2, o, 64));
        m3 = fmaxf(m3, __shfl_down(m3, o, 64));
    }
    if (lane == 0) { smx[wid][0] = m0; smx[wid][1] = m1; smx[wid][2] = m2; smx[wid][3] = m3; }
    __syncthreads();
    float e[HH];
    float e0, e1, e2, e3;
    {
        float mh0 = fmaxf(fmaxf(smx[0][0], smx[1][0]), fmaxf(smx[2][0], smx[3][0]));
        float mh1 = fmaxf(fmaxf(smx[0][1], smx[1][1]), fmaxf(smx[2][1], smx[3][1]));
        float mh2 = fmaxf(fmaxf(smx[0][2], smx[1][2]), fmaxf(smx[2][2], smx[3][2]));
        float mh3 = fmaxf(fmaxf(smx[0][3], smx[1][3]), fmaxf(smx[2][3], smx[3][3]));
        bool act = (s <= t);
        e[0] = e0 = act ? expf(val[0] - mh0) : 0.0f;
        e[1] = e1 = act ? expf(val[1] - mh1) : 0.0f;
        e[2] = e2 = act ? expf(val[2] - mh2) : 0.0f;
        e[3] = e3 = act ? expf(val[3] - mh3) : 0.0f;
    }
    // batched block sum
    #pragma unroll
    for (int o = 32; o > 0; o >>= 1) {
        e0 += __shfl_down(e0, o, 64);
        e1 += __shfl_down(e1, o, 64);
        e2 += __shfl_down(e2, o, 64);
        e3 += __shfl_down(e3, o, 64);
    }
    if (lane == 0) { ssm[wid][0] = e0; ssm[wid][1] = e1; ssm[wid][2] = e2; ssm[wid][3] = e3; }
    __syncthreads();
    float acc = 0.0f;
    #pragma unroll
    for (int h = 0; h < HH; h++) {
        float sum = ssm[0][h] + ssm[1][h] + ssm[2][h] + ssm[3][h];
        acc += e[h] / sum;
    }
    am[((size_t)b * TT + t) * TT + s] = acc * 0.25f;
}

// ---------------- fp32 NN GEMM — used only for a = am @ v ----------------
__global__ __launch_bounds__(256) void gemm_nn_k(const float* __restrict__ A,
                                                 const float* __restrict__ B,
                                                 float* __restrict__ C,
                                                 int M, int N, int K,
                                                 long lda, long ldb, long ldc,
                                                 long sAz, long sBz, long sCz) {
    int batch = blockIdx.z;
    A += (size_t)batch * sAz;
    B += (size_t)batch * sBz;
    C += (size_t)batch * sCz;
    int m0 = blockIdx.y * 64, n0 = blockIdx.x * 64;
    __shared__ float As[16][68];
    __shared__ float Bs[16][64];
    int tid = threadIdx.x;
    int tx = tid & 15, ty = tid >> 4;
    int ar = tid >> 2, ac = (tid & 3) * 4;
    int br = tid >> 4, bc = (tid & 15) * 4;
    float acc[4][4] = {};
    for (int k0 = 0; k0 < K; k0 += 16) {
        float4 av = *(const float4*)(A + (size_t)(m0 + ar) * lda + k0 + ac);
        float4 bv = *(const float4*)(B + (size_t)(k0 + br) * ldb + n0 + bc);
        As[ac + 0][ar] = av.x; As[ac + 1][ar] = av.y;
        As[ac + 2][ar] = av.z; As[ac + 3][ar] = av.w;
        *(float4*)&Bs[br][bc] = bv;
        __syncthreads();
        #pragma unroll
        for (int k = 0; k < 16; k++) {
            float4 a4 = *(const float4*)&As[k][ty * 4];
            float4 b4 = *(const float4*)&Bs[k][tx * 4];
            float aa[4] = {a4.x, a4.y, a4.z, a4.w};
            float bb[4] = {b4.x, b4.y, b4.z, b4.w};
            #pragma unroll
            for (int i = 0; i < 4; i++)
                #pragma unroll
                for (int j = 0; j < 4; j++)
                    acc[i][j] = fmaf(aa[i], bb[j], acc[i][j]);
        }
        __syncthreads();
    }
    #pragma unroll
    for (int i = 0; i < 4; i++) {
        int m = m0 + ty * 4 + i;
        #pragma unroll
        for (int j = 0; j < 4; j++) {
            int col = n0 + tx * 4 + j;
            C[(size_t)m * ldc + col] = acc[i][j];
        }
    }
}

// ---------------- launch ----------------
extern "C" void kernel_launch(void* const* d_in, const int* in_sizes, int n_in,
                              void* d_out, int out_size, void* d_ws, size_t ws_size,
                              hipStream_t stream) {
    const int*   idx  = (const int*)d_in[0];
    const float* wte  = (const float*)d_in[1];
    const float* enc  = (const float*)d_in[2];
    const float* Wx   = (const float*)d_in[3];
    const float* Wy   = (const float*)d_in[4];
    const float* Wro  = (const float*)d_in[5];
    float* out = (float*)d_out;

    // float region: v, am, a (512 KB each) + red (12 MB scores partials)
    float* ws   = (float*)d_ws;
    float* v    = ws;                  // 131072
    float* am   = v   + 131072;        // 131072
    float* a    = am  + 131072;        // 131072
    float* red  = a   + 131072;        // 3,145,728 floats (12 MB) — scp
    // short region (118 MB; total 132.1 MB, same as R7 verified footprint)
    unsigned short* sbase = (unsigned short*)(red + 3145728);
    unsigned short* vb    = sbase;                 // 131072
    unsigned short* lAb   = vb    + 131072;        // 131072
    unsigned short* ybreg = lAb   + 131072;        // 16777216: ybf during layer; WroT at end
    unsigned short* xrb   = ybreg + 16777216;      // 16777216: xrb; yencp aliases post-mode1
    unsigned short* WxT   = xrb   + 16777216;      // 8388608  [h][8192][256]
    unsigned short* WyT   = WxT   + 8388608;       // 8388608
    unsigned short* encT  = WyT   + 8388608;       // 8388608  [256][32768]
    unsigned short* ybf   = ybreg;                 // mode1 output (B,T,N)
    unsigned short* WroT  = ybreg;                 // after loop (ybf dead)
    float* yencp = (float*)xrb;                    // EKC x 131072 floats = 16 MB (fits 32 MB
                                                   // region); xrb dead after mode1 reads it

    // pre-pass: weight transpose+convert (once per launch, amortized over 6 layers)
    tconv_k<<<dim3(nn / 64, DD / 64, HH), 256, 0, stream>>>(Wx, WxT, DD, nn,
        (long)DD * nn, (long)nn * DD);
    tconv_k<<<dim3(DD / 64, NN / 64, 1), 256, 0, stream>>>(enc, encT, NN, DD, 0L, 0L);
    tconv_k<<<dim3(nn / 64, DD / 64, HH), 256, 0, stream>>>(Wy, WyT, DD, nn,
        (long)DD * nn, (long)nn * DD);

    // v = ln(wte[idx]) (+ bf16)
    embed_ln_k<<<BB * TT, 256, 0, stream>>>(idx, wte, v, vb);

    for (int l = 0; l < L_LAYERS; l++) {
        // xrb = rope(bf16(relu(vb @ WxT[h])))  — xb never written
        gemm_head_bt<<<dim3(nn / 128, (BB * TT) / 128, HH), 256, 0, stream>>>(
            vb, WxT, nullptr, xrb, 0);

        // scores partials (plain stores, no memset, no atomics)
        scores_bt<<<dim3(3, SKC, BB * HH), 256, 0, stream>>>(xrb, red);

        // softmax (causal, sums partials, batched 4-head reductions) + mean over heads
        softmax_mean_k<<<BB * TT, 256, 0, stream>>>(red, am);

        // a = am @ v (per b), fp32
        gemm_nn_k<<<dim3(DD / 64, TT / 64, BB), 256, 0, stream>>>(
            am, v, a, TT, DD, TT,
            (long)TT, (long)DD, (long)DD,
            (long)TT * TT, (long)TT * DD, (long)TT * DD);

        // lAb = bf16(ln(a))
        ln_rows_k<<<BB * TT, 256, 0, stream>>>(a, lAb);

        // ybf = bf16(relu(lAb @ WyT[h]) * inv_rope(xrb))   (ybf in ybreg)
        gemm_head_bt<<<dim3(nn / 128, (BB * TT) / 128, HH), 256, 0, stream>>>(
            lAb, WyT, xrb, ybf, 1);

        // yencp[kc] = partial ybf @ enc (plain stores into xrb region — xrb dead)
        gemm_enc_bt<<<dim3(2, 4, EKC), 256, 0, stream>>>(ybf, encT, yencp);

        // v = ln(v + ln(sum yencp)) (+ bf16)
        add_ln_ln_k<<<BB * TT, 256, 0, stream>>>(v, yencp, vb);
    }

    // WroT = transpose+bf16(Wro) into ybreg (ybf dead now)
    tconv_k<<<dim3(VV / 64, DD / 64, 1), 256, 0, stream>>>(Wro, WroT, DD, VV, 0L, 0L);

    // out = vb @ WroT^T (fp32 out)
    gemm_ro_bt<<<dim3(VV / 128, (BB * TT) / 128, 1), 256, 0, stream>>>(vb, WroT, out);
}